// Round 9
// baseline (288.198 us; speedup 1.0000x reference)
//
#include <hip/hip_runtime.h>
#include <math.h>

#define DIMC 96
#define DINC 192
#define NSTC 16
#define DTRC 6
#define KDIR 4
#define BB   2
#define HH   56
#define WWD  56
#define LL   3136
#define NPIX (BB*LL)           // 6272
#define EPSF 1e-5f
#define NCH  49                // chunks per chain
#define LC   64                // chunk length
#define NCHAIN (BB*KDIR*DINC)  // 1536
#define NCOLS 152              // 4*38

// ---------- workspace layout (float offsets) ----------
#define OFF_XN     0u          // 602112  sumdT during scan; H3 later
#define OFF_XCRAW  602112u     // 1204224 xc pre-conv NCHW; hendT during scan; y_t after
#define OFF_ZS     1806336u    // 1204224 silu(z)
#define OFF_XCONV  3010560u    // 1204224 silu(conv(xc)) NCHW
#define OFF_DTS    4214784u    // 150528  dts (B,K,L,6)
#define OFF_BCB    4365312u    // 401408  B (bk,l,n)
#define OFF_BCC    4766720u    // 401408  C (bk,l,n)
#define OFF_XCONVT 5168128u    // 1204224 transposed xconv (dead after pass1)
#define OFF_CUMD   6372352u    // 4816896 cumΔ (chain,l) (dead after pass2)
#define OFF_YS     14801920u   // 4816896 ys (B,K,192,L)
#define OFF_HENDT  OFF_XCRAW   // 8*49*16*192 = 1204224 exactly
#define OFF_SUMDT  OFF_XN      // 8*49*192 = 75264
#define OFF_YT     OFF_XCRAW
#define OFF_VL     OFF_XCONVT              // 602112 (xconvT dead after pass1)
#define OFF_H1     (OFF_XCONVT + 1300000u) // (cumd dead after pass2)
#define OFF_H2     (OFF_XCONVT + 1500000u)
#define OFF_H3     OFF_XN
#define OFF_POOL   (OFF_XCONVT + 1700000u)
#define OFF_SEW    (OFF_XCONVT + 1700448u)

__device__ __forceinline__ float siluf(float x) { return x / (1.f + __expf(-x)); }
__device__ __forceinline__ float softplusf(float x) {
    return fmaxf(x, 0.f) + __logf(1.f + __expf(-fabsf(x)));
}

// ---------- 1. fused LN1 + in_proj GEMM. grid (98,4) x 256 ----------
__global__ __launch_bounds__(256) void gemm1_k(const float* __restrict__ x,
                                               const float* __restrict__ g,
                                               const float* __restrict__ bt,
                                               const float* __restrict__ W,
                                               float* __restrict__ xcr,
                                               float* __restrict__ zs) {
    __shared__ float xT[64 * 97];
    __shared__ float wT[96 * 100];
    __shared__ float mA[64], iA[64];
    int row0 = blockIdx.x * 64;
    int b = row0 / LL, pos0 = row0 % LL;
    int c0 = blockIdx.y * 96;
    for (int f = threadIdx.x; f < 96 * 16; f += 256) {
        int ch = f >> 4, po = (f & 15) * 4;
        float4 v = *(const float4*)&x[((size_t)b * DIMC + ch) * LL + pos0 + po];
        xT[(po + 0) * 97 + ch] = v.x; xT[(po + 1) * 97 + ch] = v.y;
        xT[(po + 2) * 97 + ch] = v.z; xT[(po + 3) * 97 + ch] = v.w;
    }
    for (int f = threadIdx.x; f < 96 * 24; f += 256) {
        int r = f / 24, kq = (f % 24) * 4;
        *(float4*)&wT[r * 100 + kq] = *(const float4*)&W[(size_t)(c0 + r) * DIMC + kq];
    }
    __syncthreads();
    if (threadIdx.x < 64) {
        float s = 0.f, q = 0.f;
        const float* xr = &xT[threadIdx.x * 97];
        for (int c = 0; c < 96; ++c) { float v = xr[c]; s += v; q = fmaf(v, v, q); }
        float m = s * (1.f / 96.f);
        mA[threadIdx.x] = m;
        iA[threadIdx.x] = rsqrtf(q * (1.f / 96.f) - m * m + EPSF);
    }
    __syncthreads();
    for (int e = threadIdx.x; e < 64 * 96; e += 256) {
        int row = e / 96, col = e - row * 96;
        float v = xT[row * 97 + col];
        xT[row * 97 + col] = (v - mA[row]) * iA[row] * g[col] + bt[col];
    }
    __syncthreads();
    int tc = threadIdx.x & 15, tr = threadIdx.x >> 4;
    float acc[4][6] = {};
    for (int k = 0; k < 96; ++k) {
        float xv[4], wv[6];
#pragma unroll
        for (int i = 0; i < 4; ++i) xv[i] = xT[(4 * tr + i) * 97 + k];
#pragma unroll
        for (int j = 0; j < 6; ++j) wv[j] = wT[(tc + 16 * j) * 100 + k];
#pragma unroll
        for (int i = 0; i < 4; ++i)
#pragma unroll
            for (int j = 0; j < 6; ++j) acc[i][j] = fmaf(xv[i], wv[j], acc[i][j]);
    }
    int pos = pos0 + 4 * tr;
    if (c0 < DINC) {
#pragma unroll
        for (int j = 0; j < 6; ++j) {
            int col = c0 + tc + 16 * j;
            float4 v = make_float4(acc[0][j], acc[1][j], acc[2][j], acc[3][j]);
            *(float4*)&xcr[((size_t)b * DINC + col) * LL + pos] = v;
        }
    } else {
#pragma unroll
        for (int i = 0; i < 4; ++i)
#pragma unroll
            for (int j = 0; j < 6; ++j) {
                int zc = c0 - DINC + tc + 16 * j;
                zs[(size_t)(row0 + 4 * tr + i) * DINC + zc] = siluf(acc[i][j]);
            }
    }
}

// ---------- 2. depthwise 3x3 conv + silu, emits xconv AND xconvT ----------
__global__ __launch_bounds__(448) void dwconvt_k(const float* __restrict__ xcr,
                                                 const float* __restrict__ cw,
                                                 const float* __restrict__ cb,
                                                 float* __restrict__ xconv,
                                                 float* __restrict__ xconvT) {
    __shared__ float P[56 * 57];
    __shared__ float T[56 * 57];
    int bd = blockIdx.x;
    int d = bd % DINC;
    size_t base = (size_t)bd * LL;
    for (int t = threadIdx.x; t < LL; t += 448)
        P[(t / 56) * 57 + (t % 56)] = xcr[base + t];
    float wk[9];
#pragma unroll
    for (int q = 0; q < 9; ++q) wk[q] = cw[d * 9 + q];
    float bias = cb[d];
    __syncthreads();
    for (int t = threadIdx.x; t < LL; t += 448) {
        int h = t / 56, w = t % 56;
        float acc = bias;
#pragma unroll
        for (int ky = 0; ky < 3; ++ky) {
            int y = h + ky - 1;
            if ((unsigned)y >= 56u) continue;
#pragma unroll
            for (int kx = 0; kx < 3; ++kx) {
                int xq = w + kx - 1;
                if ((unsigned)xq >= 56u) continue;
                acc = fmaf(wk[ky * 3 + kx], P[y * 57 + xq], acc);
            }
        }
        float v = siluf(acc);
        xconv[base + t] = v;
        T[w * 57 + h] = v;
    }
    __syncthreads();
    for (int t = threadIdx.x; t < LL; t += 448)
        xconvT[base + t] = T[(t / 56) * 57 + (t % 56)];
}

// ---------- 3. x_proj LDS-tiled GEMM -> scattered dts/bcB/bcC. grid 98 x 256 ----------
__global__ __launch_bounds__(256) void gemmx_k(const float* __restrict__ xconv,
                                               const float* __restrict__ xpw,
                                               float* __restrict__ dts,
                                               float* __restrict__ bcB,
                                               float* __restrict__ bcC) {
    __shared__ float xT[64 * 49];
    __shared__ float wT[NCOLS * 52];
    int row0 = blockIdx.x * 64;
    int b = row0 / LL, pos0 = row0 % LL;
    int tc = threadIdx.x & 15, tr = threadIdx.x >> 4;
    float acc[4][10] = {};
    for (int kc = 0; kc < 4; ++kc) {
        if (kc) __syncthreads();
        for (int f = threadIdx.x; f < 48 * 16; f += 256) {
            int dd = f >> 4, po = (f & 15) * 4;
            float4 v = *(const float4*)&xconv[((size_t)b * DINC + kc * 48 + dd) * LL + pos0 + po];
            xT[(po + 0) * 49 + dd] = v.x; xT[(po + 1) * 49 + dd] = v.y;
            xT[(po + 2) * 49 + dd] = v.z; xT[(po + 3) * 49 + dd] = v.w;
        }
        for (int f = threadIdx.x; f < NCOLS * 12; f += 256) {
            int r = f / 12, kq = (f % 12) * 4;
            *(float4*)&wT[r * 52 + kq] = *(const float4*)&xpw[(size_t)r * DINC + kc * 48 + kq];
        }
        __syncthreads();
        for (int k = 0; k < 48; ++k) {
            float xv[4], wv[10];
#pragma unroll
            for (int i = 0; i < 4; ++i) xv[i] = xT[(4 * tr + i) * 49 + k];
#pragma unroll
            for (int j = 0; j < 10; ++j) {
                int c = tc + 16 * j;
                wv[j] = (c < NCOLS) ? wT[c * 52 + k] : 0.f;
            }
#pragma unroll
            for (int i = 0; i < 4; ++i)
#pragma unroll
                for (int j = 0; j < 10; ++j) acc[i][j] = fmaf(xv[i], wv[j], acc[i][j]);
        }
    }
#pragma unroll
    for (int i = 0; i < 4; ++i) {
        int pos = pos0 + 4 * tr + i;
        int h = pos / 56, w = pos - 56 * h;
        int lt = w * 56 + h;
#pragma unroll
        for (int j = 0; j < 10; ++j) {
            int c = tc + 16 * j;
            if (c >= NCOLS) continue;
            int k = c / 38, idx = c - 38 * k;
            int l = (k == 0) ? pos : (k == 1) ? lt : (k == 2) ? (LL - 1 - pos) : (LL - 1 - lt);
            size_t rb = (size_t)(b * KDIR + k) * LL + l;
            float v = acc[i][j];
            if (idx < DTRC)    dts[rb * DTRC + idx] = v;
            else if (idx < 22) bcB[rb * NSTC + (idx - 6)] = v;
            else               bcC[rb * NSTC + (idx - 22)] = v;
        }
    }
}

// ---------- 4a. pass1: d-per-thread local scan. grid 8*3*49=1176 x 64 ----------
__global__ __launch_bounds__(64) void pass1_k(const float* __restrict__ dts,
                                              const float* __restrict__ bcB,
                                              const float* __restrict__ bcC,
                                              const float* __restrict__ alog,
                                              const float* __restrict__ dtw,
                                              const float* __restrict__ dtb,
                                              const float* __restrict__ xconv,
                                              const float* __restrict__ xconvT,
                                              float* __restrict__ hendT,
                                              float* __restrict__ sumdT,
                                              float* __restrict__ ys,
                                              float* __restrict__ cumd) {
    __shared__ float sx[64 * 65];       // x, then y flushed in-place per 16-col block
    __shared__ float sdt[64 * 7];
    __shared__ float sB[64 * 16];
    __shared__ float sC[64 * 16];
    __shared__ float scd[64 * 17];
    int blk = blockIdx.x;
    int c = blk % NCH;
    int dtile = (blk / NCH) % 3;
    int bk = blk / (NCH * 3);
    int k = bk & 3, b = bk >> 2;
    int l0 = c * LC;
    int t = threadIdx.x;
    int d = dtile * 64 + t;
    // stage dts (padded stride 7)
    const float* dsrc = dts + ((size_t)bk * LL + l0) * DTRC;
    for (int f = t; f < LC * DTRC; f += 64) sdt[(f / DTRC) * 7 + (f % DTRC)] = dsrc[f];
    // stage B, C (contiguous)
    const float* bB = bcB + ((size_t)bk * LL + l0) * NSTC;
    const float* bC = bcC + ((size_t)bk * LL + l0) * NSTC;
    for (int f = t; f < LC * NSTC; f += 64) { sB[f] = bB[f]; sC[f] = bC[f]; }
    // stage x (coalesced per row; reversed rows still line-contiguous)
    {
        bool rev = (k >= 2);
        const float* xs = (k & 1) ? xconvT : xconv;
        for (int f = t; f < 64 * LC; f += 64) {
            int d_loc = f >> 6, s = f & 63;
            size_t row = ((size_t)b * DINC + dtile * 64 + d_loc) * LL;
            sx[d_loc * 65 + s] = xs[row + (rev ? (LL - 1 - (l0 + s)) : (l0 + s))];
        }
    }
    // per-thread parameters
    float wr[DTRC], An[NSTC];
    {
        const float* wp = dtw + ((size_t)k * DINC + d) * DTRC;
#pragma unroll
        for (int r = 0; r < DTRC; ++r) wr[r] = wp[r];
    }
    float bias = dtb[k * DINC + d];
    {
        const float* ap = alog + ((size_t)(k * DINC + d)) * NSTC;
#pragma unroll
        for (int n = 0; n < NSTC; ++n) An[n] = -__expf(ap[n]);
    }
    __syncthreads();
    float h[NSTC];
#pragma unroll
    for (int n = 0; n < NSTC; ++n) h[n] = 0.f;
    float cum = 0.f;
    for (int q = 0; q < 4; ++q) {
        float y16[16], cd16[16];
#pragma unroll
        for (int j = 0; j < 16; ++j) {
            int s = q * 16 + j;
            float acc = bias;
#pragma unroll
            for (int r = 0; r < DTRC; ++r) acc = fmaf(wr[r], sdt[s * 7 + r], acc);
            float dv = softplusf(acc);
            float dx = dv * sx[t * 65 + s];
            cum += dv;
            const float4* B4 = (const float4*)&sB[s * 16];
            const float4* C4 = (const float4*)&sC[s * 16];
            float y = 0.f;
#pragma unroll
            for (int nq = 0; nq < 4; ++nq) {
                float4 Bv = B4[nq], Cv = C4[nq];
                float e0 = __expf(An[nq * 4 + 0] * dv);
                h[nq * 4 + 0] = fmaf(e0, h[nq * 4 + 0], dx * Bv.x);
                y = fmaf(h[nq * 4 + 0], Cv.x, y);
                float e1 = __expf(An[nq * 4 + 1] * dv);
                h[nq * 4 + 1] = fmaf(e1, h[nq * 4 + 1], dx * Bv.y);
                y = fmaf(h[nq * 4 + 1], Cv.y, y);
                float e2 = __expf(An[nq * 4 + 2] * dv);
                h[nq * 4 + 2] = fmaf(e2, h[nq * 4 + 2], dx * Bv.z);
                y = fmaf(h[nq * 4 + 2], Cv.z, y);
                float e3 = __expf(An[nq * 4 + 3] * dv);
                h[nq * 4 + 3] = fmaf(e3, h[nq * 4 + 3], dx * Bv.w);
                y = fmaf(h[nq * 4 + 3], Cv.w, y);
            }
            y16[j] = y; cd16[j] = cum;
        }
        // transpose-flush y/cumd (overwrite consumed x columns)
#pragma unroll
        for (int j = 0; j < 16; ++j) {
            sx[t * 65 + q * 16 + j] = y16[j];
            scd[t * 17 + j] = cd16[j];
        }
        __syncthreads();
#pragma unroll
        for (int i = 0; i < 16; ++i) {
            int row = i * 4 + (t >> 4);
            int col = t & 15;
            size_t gaddr = ((size_t)bk * DINC + dtile * 64 + row) * LL + l0 + q * 16 + col;
            ys[gaddr] = sx[row * 65 + q * 16 + col];
            cumd[gaddr] = scd[row * 17 + col];
        }
        __syncthreads();
    }
#pragma unroll
    for (int n = 0; n < NSTC; ++n)
        hendT[((size_t)(bk * NCH + c) * NSTC + n) * DINC + d] = h[n];
    sumdT[(size_t)(bk * NCH + c) * DINC + d] = cum;
}

// ---------- 4b. scan2: thread=(d,n), serial over chunks. grid 96 x 256 ----------
__global__ __launch_bounds__(256) void scan2_k(float* __restrict__ hendT,
                                               const float* __restrict__ sumdT,
                                               const float* __restrict__ alog) {
    int gid = blockIdx.x * 256 + threadIdx.x;   // = (bk*16+n)*192 + d
    int d = gid % DINC;
    int n = (gid / DINC) % NSTC;
    int bk = gid / (DINC * NSTC);
    int k = bk & 3;
    float An = -__expf(alog[((size_t)(k * DINC + d)) * NSTC + n]);
    float h = 0.f;
    for (int c = 0; c < NCH; ++c) {
        size_t idx = ((size_t)(bk * NCH + c) * NSTC + n) * DINC + d;
        float he = hendT[idx];
        float sd = sumdT[(size_t)(bk * NCH + c) * DINC + d];
        hendT[idx] = h;                          // h_pre for chunk c
        h = fmaf(__expf(An * sd), h, he);
    }
}

// ---------- 4c. pass2: y += sum_n C_n*exp(An*cumd)*hpre_n. grid 1176 x 256 ----------
__global__ __launch_bounds__(256) void pass2_k(const float* __restrict__ bcC,
                                               const float* __restrict__ alog,
                                               const float* __restrict__ hpreT,
                                               const float* __restrict__ cumd,
                                               float* __restrict__ ys) {
    __shared__ float sA[64 * NSTC];
    __shared__ float sH[64 * NSTC];
    __shared__ float sCt[NSTC * 68];
    int blk = blockIdx.x;
    int c = blk % NCH;
    int dtile = (blk / NCH) % 3;
    int bk = blk / (NCH * 3);
    int k = bk & 3;
    int l0 = c * LC;
    int tid = threadIdx.x;
    {
        const float* ap = alog + ((size_t)(k * DINC + dtile * 64)) * NSTC;
        for (int f = tid; f < 64 * NSTC; f += 256) sA[f] = -__expf(ap[f]);
        for (int f = tid; f < 64 * NSTC; f += 256) {
            int n = f >> 6, dq = f & 63;
            sH[dq * NSTC + n] =
                hpreT[((size_t)(bk * NCH + c) * NSTC + n) * DINC + dtile * 64 + dq];
        }
        const float* bC = bcC + ((size_t)bk * LL + l0) * NSTC;
        for (int f = tid; f < LC * NSTC; f += 256) {
            int s = f >> 4, n = f & 15;
            sCt[n * 68 + s] = bC[f];
        }
    }
    __syncthreads();
    int w = tid >> 6, s = tid & 63;
#pragma unroll 4
    for (int dd = 0; dd < 16; ++dd) {
        int d = w * 16 + dd;
        size_t row = ((size_t)bk * DINC + dtile * 64 + d) * LL + l0 + s;
        float cd = cumd[row];
        float y = ys[row];
#pragma unroll
        for (int n = 0; n < NSTC; ++n) {
            float t = __expf(sA[d * NSTC + n] * cd);
            y = fmaf(sH[d * NSTC + n] * t, sCt[n * 68 + s], y);
        }
        ys[row] = y;
    }
}

// ---------- 5. combine 4 directions (+ D*x) with in-LDS transpose ----------
__global__ __launch_bounds__(448) void combine_k(const float* __restrict__ ys,
                                                 const float* __restrict__ xconv,
                                                 const float* __restrict__ dsv,
                                                 float* __restrict__ yt) {
    __shared__ float T[56 * 57];
    int bd = blockIdx.x;
    int d = bd % DINC, b = bd / DINC;
    const float* y0 = ys + ((size_t)(b * KDIR + 0) * DINC + d) * LL;
    const float* y1 = ys + ((size_t)(b * KDIR + 1) * DINC + d) * LL;
    const float* y2 = ys + ((size_t)(b * KDIR + 2) * DINC + d) * LL;
    const float* y3 = ys + ((size_t)(b * KDIR + 3) * DINC + d) * LL;
    for (int l = threadIdx.x; l < LL; l += 448)
        T[(l % 56) * 57 + (l / 56)] = y1[l] + y3[LL - 1 - l];
    float sD = dsv[d] + dsv[DINC + d] + dsv[2 * DINC + d] + dsv[3 * DINC + d];
    size_t base = (size_t)bd * LL;
    __syncthreads();
    for (int pos = threadIdx.x; pos < LL; pos += 448) {
        float y = y0[pos] + y2[LL - 1 - pos] + T[(pos / 56) * 57 + (pos % 56)];
        yt[base + pos] = fmaf(xconv[base + pos], sD, y);
    }
}

// ---------- 6. fused out_norm*silu(z) + out_proj + residual ----------
__global__ __launch_bounds__(256) void gemm2_k(const float* __restrict__ yt,
                                               const float* __restrict__ g,
                                               const float* __restrict__ bt,
                                               const float* __restrict__ zs,
                                               const float* __restrict__ opw,
                                               const float* __restrict__ x,
                                               const float* __restrict__ sc1,
                                               float* __restrict__ vl) {
    __shared__ float xT[64 * 193];
    __shared__ float wT[96 * 52];
    __shared__ float mA[64], iA[64];
    int row0 = blockIdx.x * 64;
    int b = row0 / LL, pos0 = row0 % LL;
    for (int f = threadIdx.x; f < 192 * 16; f += 256) {
        int ch = f >> 4, po = (f & 15) * 4;
        float4 v = *(const float4*)&yt[((size_t)b * DINC + ch) * LL + pos0 + po];
        xT[(po + 0) * 193 + ch] = v.x; xT[(po + 1) * 193 + ch] = v.y;
        xT[(po + 2) * 193 + ch] = v.z; xT[(po + 3) * 193 + ch] = v.w;
    }
    __syncthreads();
    if (threadIdx.x < 64) {
        float s = 0.f, q = 0.f;
        const float* xr = &xT[threadIdx.x * 193];
        for (int c = 0; c < 192; ++c) { float v = xr[c]; s += v; q = fmaf(v, v, q); }
        float m = s * (1.f / 192.f);
        mA[threadIdx.x] = m;
        iA[threadIdx.x] = rsqrtf(q * (1.f / 192.f) - m * m + EPSF);
    }
    __syncthreads();
    for (int e = threadIdx.x; e < 64 * 192; e += 256) {
        int row = e / 192, col = e - row * 192;
        float v = xT[row * 193 + col];
        float z = zs[(size_t)row0 * DINC + e];
        xT[row * 193 + col] = ((v - mA[row]) * iA[row] * g[col] + bt[col]) * z;
    }
    int tc = threadIdx.x & 15, tr = threadIdx.x >> 4;
    float acc[4][6] = {};
    for (int kc = 0; kc < 4; ++kc) {
        __syncthreads();
        for (int f = threadIdx.x; f < 96 * 12; f += 256) {
            int r = f / 12, kq = (f % 12) * 4;
            *(float4*)&wT[r * 52 + kq] = *(const float4*)&opw[(size_t)r * DINC + kc * 48 + kq];
        }
        __syncthreads();
        for (int k = 0; k < 48; ++k) {
            float xv[4], wv[6];
#pragma unroll
            for (int i = 0; i < 4; ++i) xv[i] = xT[(4 * tr + i) * 193 + kc * 48 + k];
#pragma unroll
            for (int j = 0; j < 6; ++j) wv[j] = wT[(tc + 16 * j) * 52 + k];
#pragma unroll
            for (int i = 0; i < 4; ++i)
#pragma unroll
                for (int j = 0; j < 6; ++j) acc[i][j] = fmaf(xv[i], wv[j], acc[i][j]);
        }
    }
#pragma unroll
    for (int i = 0; i < 4; ++i) {
        int pos = pos0 + 4 * tr + i;
#pragma unroll
        for (int j = 0; j < 6; ++j) {
            int col = tc + 16 * j;
            float v = fmaf(sc1[col], x[((size_t)b * DIMC + col) * LL + pos], acc[i][j]);
            vl[(size_t)(row0 + 4 * tr + i) * DIMC + col] = v;
        }
    }
}

// ---------- 7. LN2 + conv1x1(96->24) + BN + ReLU ----------
__global__ __launch_bounds__(256) void ln2conv1_k(const float* __restrict__ vl,
                                                  const float* __restrict__ g,
                                                  const float* __restrict__ bt,
                                                  const float* __restrict__ w1,
                                                  const float* __restrict__ g1,
                                                  const float* __restrict__ b1,
                                                  const float* __restrict__ m1,
                                                  const float* __restrict__ v1,
                                                  float* __restrict__ h1) {
    __shared__ float row[4][96];
    int wv = threadIdx.x >> 6, lane = threadIdx.x & 63;
    int pix = blockIdx.x * 4 + wv;
    const float* vr = vl + (size_t)pix * DIMC;
    float a0 = vr[lane];
    float a1 = (lane < 32) ? vr[64 + lane] : 0.f;
    float s = a0 + a1, q = a0 * a0 + a1 * a1;
    for (int o = 32; o; o >>= 1) { s += __shfl_xor(s, o, 64); q += __shfl_xor(q, o, 64); }
    float m = s * (1.f / 96.f);
    float inv = rsqrtf(q * (1.f / 96.f) - m * m + EPSF);
    row[wv][lane] = (a0 - m) * inv * g[lane] + bt[lane];
    if (lane < 32) row[wv][64 + lane] = (a1 - m) * inv * g[64 + lane] + bt[64 + lane];
    __syncthreads();
    if (lane < 24) {
        const float* wr = w1 + lane * 96;
        float acc = 0.f;
#pragma unroll 8
        for (int c = 0; c < 96; ++c) acc = fmaf(row[wv][c], wr[c], acc);
        float bn = (acc - m1[lane]) * rsqrtf(v1[lane] + EPSF) * g1[lane] + b1[lane];
        int b = pix / LL, pos = pix % LL;
        h1[((size_t)b * 24 + lane) * LL + pos] = fmaxf(bn, 0.f);
    }
}

// ---------- 8. conv3x3 (24->24) + BN + ReLU ----------
__global__ __launch_bounds__(256) void conv2_k(const float* __restrict__ h1,
                                               const float* __restrict__ w2,
                                               const float* __restrict__ g2,
                                               const float* __restrict__ b2,
                                               const float* __restrict__ m2,
                                               const float* __restrict__ v2,
                                               float* __restrict__ h2) {
    int i = blockIdx.x * 256 + threadIdx.x;
    int pos = i % LL, mo = (i / LL) % 24, b = i / (LL * 24);
    int hh = pos / WWD, ww = pos % WWD;
    float acc = 0.f;
    for (int c = 0; c < 24; ++c) {
        const float* src = h1 + ((size_t)b * 24 + c) * LL;
        const float* wk = w2 + ((size_t)(mo * 24 + c)) * 9;
#pragma unroll
        for (int ky = 0; ky < 3; ++ky) {
            int y = hh + ky - 1;
            if ((unsigned)y >= HH) continue;
#pragma unroll
            for (int kx = 0; kx < 3; ++kx) {
                int xq = ww + kx - 1;
                if ((unsigned)xq >= WWD) continue;
                acc = fmaf(wk[ky * 3 + kx], src[y * WWD + xq], acc);
            }
        }
    }
    float bn = (acc - m2[mo]) * rsqrtf(v2[mo] + EPSF) * g2[mo] + b2[mo];
    h2[i] = fmaxf(bn, 0.f);
}

// ---------- 9. conv1x1 (24->96) + BN ----------
__global__ __launch_bounds__(256) void conv3_k(const float* __restrict__ h2,
                                               const float* __restrict__ w3,
                                               const float* __restrict__ g3,
                                               const float* __restrict__ b3,
                                               const float* __restrict__ m3,
                                               const float* __restrict__ v3,
                                               float* __restrict__ h3) {
    int i = blockIdx.x * 256 + threadIdx.x;
    int pos = i % LL, c = (i / LL) % DIMC, b = i / (LL * DIMC);
    const float* wr = w3 + c * 24;
    float acc = 0.f;
#pragma unroll
    for (int mo = 0; mo < 24; ++mo)
        acc = fmaf(wr[mo], h2[((size_t)b * 24 + mo) * LL + pos], acc);
    h3[i] = (acc - m3[c]) * rsqrtf(v3[c] + EPSF) * g3[c] + b3[c];
}

// ---------- 10. SE pool ----------
__global__ __launch_bounds__(256) void pool_k(const float* __restrict__ h3,
                                              float* __restrict__ pooled) {
    int bc = blockIdx.x;
    const float* p = h3 + (size_t)bc * LL;
    float s = 0.f;
    for (int i = threadIdx.x; i < LL; i += 256) s += p[i];
    for (int o = 32; o; o >>= 1) s += __shfl_xor(s, o, 64);
    __shared__ float wsum[4];
    if ((threadIdx.x & 63) == 0) wsum[threadIdx.x >> 6] = s;
    __syncthreads();
    if (threadIdx.x == 0) pooled[bc] = (wsum[0] + wsum[1] + wsum[2] + wsum[3]) * (1.f / 3136.f);
}

// ---------- 11. SE MLP ----------
__global__ __launch_bounds__(128) void semlp_k(const float* __restrict__ pooled,
                                               const float* __restrict__ sw1,
                                               const float* __restrict__ sw2,
                                               float* __restrict__ sew) {
    __shared__ float pl[2][96];
    __shared__ float hid[2][24];
    for (int i = threadIdx.x; i < 192; i += 128) pl[i / 96][i % 96] = pooled[i];
    __syncthreads();
    if (threadIdx.x < 48) {
        int b = threadIdx.x / 24, mo = threadIdx.x % 24;
        float acc = 0.f;
        for (int c = 0; c < 96; ++c) acc = fmaf(pl[b][c], sw1[mo * 96 + c], acc);
        hid[b][mo] = fmaxf(acc, 0.f);
    }
    __syncthreads();
    for (int i = threadIdx.x; i < 192; i += 128) {
        int b = i / 96, c = i % 96;
        float acc = 0.f;
        for (int mo = 0; mo < 24; ++mo) acc = fmaf(hid[b][mo], sw2[c * 24 + mo], acc);
        sew[i] = 1.f / (1.f + __expf(-acc));
    }
}

// ---------- 12. final ----------
__global__ __launch_bounds__(256) void final_k(const float* __restrict__ h3,
                                               const float* __restrict__ sew,
                                               const float* __restrict__ vl,
                                               const float* __restrict__ sc2,
                                               float* __restrict__ out) {
    int i = blockIdx.x * 256 + threadIdx.x;
    int pos = i % LL, c = (i / LL) % DIMC, b = i / (LL * DIMC);
    out[i] = fmaf(h3[i], sew[b * DIMC + c],
                  sc2[c] * vl[((size_t)b * LL + pos) * DIMC + c]);
}

extern "C" void kernel_launch(void* const* d_in, const int* in_sizes, int n_in,
                              void* d_out, int out_size, void* d_ws, size_t ws_size,
                              hipStream_t stream) {
    const float* x    = (const float*)d_in[0];
    const float* n1g  = (const float*)d_in[1];
    const float* n1b  = (const float*)d_in[2];
    const float* ipw  = (const float*)d_in[3];
    const float* cw   = (const float*)d_in[4];
    const float* cb   = (const float*)d_in[5];
    const float* xpw  = (const float*)d_in[6];
    const float* dtw  = (const float*)d_in[7];
    const float* dtb  = (const float*)d_in[8];
    const float* alog = (const float*)d_in[9];
    const float* dsv  = (const float*)d_in[10];
    const float* ong  = (const float*)d_in[11];
    const float* onb  = (const float*)d_in[12];
    const float* opw  = (const float*)d_in[13];
    const float* sc1  = (const float*)d_in[14];
    const float* n2g  = (const float*)d_in[15];
    const float* n2b  = (const float*)d_in[16];
    const float* w1   = (const float*)d_in[17];
    const float* g1   = (const float*)d_in[18];
    const float* b1   = (const float*)d_in[19];
    const float* m1   = (const float*)d_in[20];
    const float* v1   = (const float*)d_in[21];
    const float* w2   = (const float*)d_in[22];
    const float* g2   = (const float*)d_in[23];
    const float* b2   = (const float*)d_in[24];
    const float* m2   = (const float*)d_in[25];
    const float* v2   = (const float*)d_in[26];
    const float* w3   = (const float*)d_in[27];
    const float* g3   = (const float*)d_in[28];
    const float* b3   = (const float*)d_in[29];
    const float* m3   = (const float*)d_in[30];
    const float* v3   = (const float*)d_in[31];
    const float* sw1  = (const float*)d_in[32];
    const float* sw2  = (const float*)d_in[33];
    const float* sc2  = (const float*)d_in[34];
    float* ws = (float*)d_ws;
    float* out = (float*)d_out;

    gemm1_k<<<dim3(NPIX / 64, 4), 256, 0, stream>>>(x, n1g, n1b, ipw,
                                                    ws + OFF_XCRAW, ws + OFF_ZS);
    dwconvt_k<<<BB * DINC, 448, 0, stream>>>(ws + OFF_XCRAW, cw, cb,
                                             ws + OFF_XCONV, ws + OFF_XCONVT);
    gemmx_k<<<NPIX / 64, 256, 0, stream>>>(ws + OFF_XCONV, xpw, ws + OFF_DTS,
                                           ws + OFF_BCB, ws + OFF_BCC);

    pass1_k<<<BB * KDIR * 3 * NCH, 64, 0, stream>>>(
        ws + OFF_DTS, ws + OFF_BCB, ws + OFF_BCC, alog, dtw, dtb,
        ws + OFF_XCONV, ws + OFF_XCONVT, ws + OFF_HENDT, ws + OFF_SUMDT,
        ws + OFF_YS, ws + OFF_CUMD);
    scan2_k<<<(NCHAIN * NSTC) / 256, 256, 0, stream>>>(ws + OFF_HENDT, ws + OFF_SUMDT, alog);
    pass2_k<<<BB * KDIR * 3 * NCH, 256, 0, stream>>>(
        ws + OFF_BCC, alog, ws + OFF_HENDT, ws + OFF_CUMD, ws + OFF_YS);

    combine_k<<<BB * DINC, 448, 0, stream>>>(ws + OFF_YS, ws + OFF_XCONV, dsv, ws + OFF_YT);
    gemm2_k<<<NPIX / 64, 256, 0, stream>>>(ws + OFF_YT, ong, onb, ws + OFF_ZS, opw, x, sc1,
                                           ws + OFF_VL);
    ln2conv1_k<<<NPIX / 4, 256, 0, stream>>>(ws + OFF_VL, n2g, n2b, w1, g1, b1, m1, v1,
                                             ws + OFF_H1);
    conv2_k<<<(BB * 24 * LL) / 256, 256, 0, stream>>>(ws + OFF_H1, w2, g2, b2, m2, v2,
                                                      ws + OFF_H2);
    conv3_k<<<(BB * DIMC * LL) / 256, 256, 0, stream>>>(ws + OFF_H2, w3, g3, b3, m3, v3,
                                                        ws + OFF_H3);
    pool_k<<<BB * DIMC, 256, 0, stream>>>(ws + OFF_H3, ws + OFF_POOL);
    semlp_k<<<1, 128, 0, stream>>>(ws + OFF_POOL, sw1, sw2, ws + OFF_SEW);
    final_k<<<(BB * DIMC * LL) / 256, 256, 0, stream>>>(ws + OFF_H3, ws + OFF_SEW, ws + OFF_VL,
                                                        sc2, out);
    (void)in_sizes; (void)n_in; (void)out_size; (void)ws_size;
}

// Round 10
// 268.603 us; speedup vs baseline: 1.0730x; 1.0730x over previous
//
#include <hip/hip_runtime.h>
#include <math.h>

#define DIMC 96
#define DINC 192
#define NSTC 16
#define DTRC 6
#define KDIR 4
#define BB   2
#define HH   56
#define WWD  56
#define LL   3136
#define NPIX (BB*LL)           // 6272
#define EPSF 1e-5f
#define NCH  56                // chunks per chain
#define LC   56                // chunk length (56*56=3136)
#define NCHAIN (BB*KDIR*DINC)  // 1536
#define NCOLS 152              // 4*38

// ---------- workspace layout (float offsets) ----------
#define OFF_HENDT  0u          // 1376256 (pass1->pass2); H3 later at 0
#define OFF_SUMDT  1376256u    // 86016
#define OFF_XCRAW  602112u     // 1204224 (gemm1->dwconv) [dead before pass1 writes hendT]
#define OFF_ZS     1806336u    // 1204224 silu(z) (gemm1->gemm2)
#define OFF_XCONV  3010560u    // 1204224 (dwconv->gemmx)
#define OFF_DTS    4214784u    // 150528  dts (bk,l,6)
#define OFF_BCB    4365312u    // 401408  B (bk,l,n)
#define OFF_BCC    4766720u    // 401408  C (bk,l,n)
#define OFF_XSCANT 5168128u    // 4816896 x in scan order, [bk][l][d] (gemmx->combine)
#define OFF_CUMD   9985024u    // 4816896 cumDelta [bk][l][d] (pass1->pass2)
#define OFF_YS     14801920u   // 4816896 y_T [bk][l][d] (pass1->combine)
// after pass2, CUMD region is reused:
#define OFF_YT     9985024u    // 1204224 yt_T [b][pos][d] (combine->gemm2)
#define OFF_VL     11189248u   // 602112
#define OFF_H1     11791360u   // 150528
#define OFF_H2     11941888u   // 150528
#define OFF_POOL   12092416u   // 192
#define OFF_SEW    12092608u   // 192
#define OFF_H3     0u          // 602112 (hendT dead by then)

__device__ __forceinline__ float siluf(float x) { return x / (1.f + __expf(-x)); }
__device__ __forceinline__ float softplusf(float x) {
    return fmaxf(x, 0.f) + __logf(1.f + __expf(-fabsf(x)));
}
__device__ __forceinline__ float fexp2(float x) {
#if __has_builtin(__builtin_amdgcn_exp2f)
    return __builtin_amdgcn_exp2f(x);
#else
    return exp2f(x);
#endif
}
#define LOG2E 1.44269504088896f

// ---------- 1. fused LN1 + in_proj GEMM. grid (98,4) x 256 ----------
__global__ __launch_bounds__(256) void gemm1_k(const float* __restrict__ x,
                                               const float* __restrict__ g,
                                               const float* __restrict__ bt,
                                               const float* __restrict__ W,
                                               float* __restrict__ xcr,
                                               float* __restrict__ zs) {
    __shared__ float xT[64 * 97];
    __shared__ float wT[96 * 100];
    __shared__ float mA[64], iA[64];
    int row0 = blockIdx.x * 64;
    int b = row0 / LL, pos0 = row0 % LL;
    int c0 = blockIdx.y * 96;
    for (int f = threadIdx.x; f < 96 * 16; f += 256) {
        int ch = f >> 4, po = (f & 15) * 4;
        float4 v = *(const float4*)&x[((size_t)b * DIMC + ch) * LL + pos0 + po];
        xT[(po + 0) * 97 + ch] = v.x; xT[(po + 1) * 97 + ch] = v.y;
        xT[(po + 2) * 97 + ch] = v.z; xT[(po + 3) * 97 + ch] = v.w;
    }
    for (int f = threadIdx.x; f < 96 * 24; f += 256) {
        int r = f / 24, kq = (f % 24) * 4;
        *(float4*)&wT[r * 100 + kq] = *(const float4*)&W[(size_t)(c0 + r) * DIMC + kq];
    }
    __syncthreads();
    if (threadIdx.x < 64) {
        float s = 0.f, q = 0.f;
        const float* xr = &xT[threadIdx.x * 97];
        for (int c = 0; c < 96; ++c) { float v = xr[c]; s += v; q = fmaf(v, v, q); }
        float m = s * (1.f / 96.f);
        mA[threadIdx.x] = m;
        iA[threadIdx.x] = rsqrtf(q * (1.f / 96.f) - m * m + EPSF);
    }
    __syncthreads();
    for (int e = threadIdx.x; e < 64 * 96; e += 256) {
        int row = e / 96, col = e - row * 96;
        float v = xT[row * 97 + col];
        xT[row * 97 + col] = (v - mA[row]) * iA[row] * g[col] + bt[col];
    }
    __syncthreads();
    int tc = threadIdx.x & 15, tr = threadIdx.x >> 4;
    float acc[4][6] = {};
    for (int k = 0; k < 96; ++k) {
        float xv[4], wv[6];
#pragma unroll
        for (int i = 0; i < 4; ++i) xv[i] = xT[(4 * tr + i) * 97 + k];
#pragma unroll
        for (int j = 0; j < 6; ++j) wv[j] = wT[(tc + 16 * j) * 100 + k];
#pragma unroll
        for (int i = 0; i < 4; ++i)
#pragma unroll
            for (int j = 0; j < 6; ++j) acc[i][j] = fmaf(xv[i], wv[j], acc[i][j]);
    }
    int pos = pos0 + 4 * tr;
    if (c0 < DINC) {
#pragma unroll
        for (int j = 0; j < 6; ++j) {
            int col = c0 + tc + 16 * j;
            float4 v = make_float4(acc[0][j], acc[1][j], acc[2][j], acc[3][j]);
            *(float4*)&xcr[((size_t)b * DINC + col) * LL + pos] = v;
        }
    } else {
#pragma unroll
        for (int i = 0; i < 4; ++i)
#pragma unroll
            for (int j = 0; j < 6; ++j) {
                int zc = c0 - DINC + tc + 16 * j;
                zs[(size_t)(row0 + 4 * tr + i) * DINC + zc] = siluf(acc[i][j]);
            }
    }
}

// ---------- 2. depthwise 3x3 conv + silu -> xconv only ----------
__global__ __launch_bounds__(448) void dwconv_k(const float* __restrict__ xcr,
                                                const float* __restrict__ cw,
                                                const float* __restrict__ cb,
                                                float* __restrict__ xconv) {
    __shared__ float P[56 * 57];
    int bd = blockIdx.x;
    int d = bd % DINC;
    size_t base = (size_t)bd * LL;
    for (int t = threadIdx.x; t < LL; t += 448)
        P[(t / 56) * 57 + (t % 56)] = xcr[base + t];
    float wk[9];
#pragma unroll
    for (int q = 0; q < 9; ++q) wk[q] = cw[d * 9 + q];
    float bias = cb[d];
    __syncthreads();
    for (int t = threadIdx.x; t < LL; t += 448) {
        int h = t / 56, w = t % 56;
        float acc = bias;
#pragma unroll
        for (int ky = 0; ky < 3; ++ky) {
            int y = h + ky - 1;
            if ((unsigned)y >= 56u) continue;
#pragma unroll
            for (int kx = 0; kx < 3; ++kx) {
                int xq = w + kx - 1;
                if ((unsigned)xq >= 56u) continue;
                acc = fmaf(wk[ky * 3 + kx], P[y * 57 + xq], acc);
            }
        }
        xconv[base + t] = siluf(acc);
    }
}

// ---------- 3. x_proj GEMM + xscan_T emit. grid 98 x 256 ----------
__global__ __launch_bounds__(256) void gemmx_k(const float* __restrict__ xconv,
                                               const float* __restrict__ xpw,
                                               float* __restrict__ dts,
                                               float* __restrict__ bcB,
                                               float* __restrict__ bcC,
                                               float* __restrict__ xscanT) {
    __shared__ float xT[64 * 49];
    __shared__ float wT[NCOLS * 52];
    int row0 = blockIdx.x * 64;
    int b = row0 / LL, pos0 = row0 % LL;
    int tc = threadIdx.x & 15, tr = threadIdx.x >> 4;
    float acc[4][10] = {};
    for (int kc = 0; kc < 4; ++kc) {
        if (kc) __syncthreads();
        for (int f = threadIdx.x; f < 48 * 16; f += 256) {
            int dd = f >> 4, po = (f & 15) * 4;
            float4 v = *(const float4*)&xconv[((size_t)b * DINC + kc * 48 + dd) * LL + pos0 + po];
            xT[(po + 0) * 49 + dd] = v.x; xT[(po + 1) * 49 + dd] = v.y;
            xT[(po + 2) * 49 + dd] = v.z; xT[(po + 3) * 49 + dd] = v.w;
        }
        for (int f = threadIdx.x; f < NCOLS * 12; f += 256) {
            int r = f / 12, kq = (f % 12) * 4;
            *(float4*)&wT[r * 52 + kq] = *(const float4*)&xpw[(size_t)r * DINC + kc * 48 + kq];
        }
        __syncthreads();
        for (int k = 0; k < 48; ++k) {
            float xv[4], wv[10];
#pragma unroll
            for (int i = 0; i < 4; ++i) xv[i] = xT[(4 * tr + i) * 49 + k];
#pragma unroll
            for (int j = 0; j < 10; ++j) {
                int c = tc + 16 * j;
                wv[j] = (c < NCOLS) ? wT[c * 52 + k] : 0.f;
            }
#pragma unroll
            for (int i = 0; i < 4; ++i)
#pragma unroll
                for (int j = 0; j < 10; ++j) acc[i][j] = fmaf(xv[i], wv[j], acc[i][j]);
        }
        // emit xscan_T for this 48-d slice (xT holds xconv transposed [pos][d])
        for (int f = threadIdx.x; f < 64 * 48; f += 256) {
            int i = f / 48, dd = f - 48 * (f / 48);
            float v = xT[i * 49 + dd];
            int pos = pos0 + i;
            int hh = pos / 56, w = pos - 56 * hh;
            int lt = w * 56 + hh;
            size_t bb = (size_t)b * KDIR;
            int col = kc * 48 + dd;
            xscanT[((bb + 0) * LL + pos) * DINC + col] = v;
            xscanT[((bb + 1) * LL + lt) * DINC + col] = v;
            xscanT[((bb + 2) * LL + (LL - 1 - pos)) * DINC + col] = v;
            xscanT[((bb + 3) * LL + (LL - 1 - lt)) * DINC + col] = v;
        }
    }
#pragma unroll
    for (int i = 0; i < 4; ++i) {
        int pos = pos0 + 4 * tr + i;
        int h = pos / 56, w = pos - 56 * h;
        int lt = w * 56 + h;
#pragma unroll
        for (int j = 0; j < 10; ++j) {
            int c = tc + 16 * j;
            if (c >= NCOLS) continue;
            int k = c / 38, idx = c - 38 * k;
            int l = (k == 0) ? pos : (k == 1) ? lt : (k == 2) ? (LL - 1 - pos) : (LL - 1 - lt);
            size_t rb = (size_t)(b * KDIR + k) * LL + l;
            float v = acc[i][j];
            if (idx < DTRC)    dts[rb * DTRC + idx] = v;
            else if (idx < 22) bcB[rb * NSTC + (idx - 6)] = v;
            else               bcC[rb * NSTC + (idx - 22)] = v;
        }
    }
}

// ---------- 4a. pass1: d-per-thread local scan, stream from xscan_T ----------
// grid: 8*3*56 = 1344 x 64
__global__ __launch_bounds__(64) void pass1_k(const float* __restrict__ dts,
                                              const float* __restrict__ bcB,
                                              const float* __restrict__ bcC,
                                              const float* __restrict__ alog,
                                              const float* __restrict__ dtw,
                                              const float* __restrict__ dtb,
                                              const float* __restrict__ xscanT,
                                              float* __restrict__ hendT,
                                              float* __restrict__ sumdT,
                                              float* __restrict__ ysT,
                                              float* __restrict__ cumdT) {
    __shared__ float sdt[LC * 7];
    __shared__ float sB[LC * 16];
    __shared__ float sC[LC * 16];
    int blk = blockIdx.x;
    int c = blk % NCH;
    int dtile = (blk / NCH) % 3;
    int bk = blk / (NCH * 3);
    int k = bk & 3;
    int l0 = c * LC;
    int t = threadIdx.x;
    int d = dtile * 64 + t;
    const float* dsrc = dts + ((size_t)bk * LL + l0) * DTRC;
    for (int f = t; f < LC * DTRC; f += 64) sdt[(f / DTRC) * 7 + (f % DTRC)] = dsrc[f];
    const float* bB = bcB + ((size_t)bk * LL + l0) * NSTC;
    const float* bC = bcC + ((size_t)bk * LL + l0) * NSTC;
    for (int f = t; f < LC * NSTC; f += 64) { sB[f] = bB[f]; sC[f] = bC[f]; }
    float wr[DTRC];
    {
        const float* wp = dtw + ((size_t)k * DINC + d) * DTRC;
#pragma unroll
        for (int r = 0; r < DTRC; ++r) wr[r] = wp[r];
    }
    float bias = dtb[k * DINC + d];
    float An2[NSTC];
    {
        const float* ap = alog + ((size_t)(k * DINC + d)) * NSTC;
#pragma unroll
        for (int n = 0; n < NSTC; ++n) An2[n] = -__expf(ap[n]) * LOG2E;
    }
    __syncthreads();
    float h[NSTC];
#pragma unroll
    for (int n = 0; n < NSTC; ++n) h[n] = 0.f;
    float cum = 0.f;
    const float* xrow = xscanT + ((size_t)bk * LL + l0) * DINC + d;
    float* yrow = ysT + ((size_t)bk * LL + l0) * DINC + d;
    float* crow = cumdT + ((size_t)bk * LL + l0) * DINC + d;
#pragma unroll 8
    for (int s = 0; s < LC; ++s) {
        float acc = bias;
#pragma unroll
        for (int r = 0; r < DTRC; ++r) acc = fmaf(wr[r], sdt[s * 7 + r], acc);
        float dv = softplusf(acc);
        float xv = xrow[(size_t)s * DINC];
        cum += dv;
        float dx = dv * xv;
        const float4* B4 = (const float4*)&sB[s * 16];
        const float4* C4 = (const float4*)&sC[s * 16];
        float y = 0.f;
#pragma unroll
        for (int nq = 0; nq < 4; ++nq) {
            float4 Bv = B4[nq], Cv = C4[nq];
            float e0 = fexp2(An2[nq * 4 + 0] * dv);
            h[nq * 4 + 0] = fmaf(e0, h[nq * 4 + 0], dx * Bv.x);
            y = fmaf(h[nq * 4 + 0], Cv.x, y);
            float e1 = fexp2(An2[nq * 4 + 1] * dv);
            h[nq * 4 + 1] = fmaf(e1, h[nq * 4 + 1], dx * Bv.y);
            y = fmaf(h[nq * 4 + 1], Cv.y, y);
            float e2 = fexp2(An2[nq * 4 + 2] * dv);
            h[nq * 4 + 2] = fmaf(e2, h[nq * 4 + 2], dx * Bv.z);
            y = fmaf(h[nq * 4 + 2], Cv.z, y);
            float e3 = fexp2(An2[nq * 4 + 3] * dv);
            h[nq * 4 + 3] = fmaf(e3, h[nq * 4 + 3], dx * Bv.w);
            y = fmaf(h[nq * 4 + 3], Cv.w, y);
        }
        yrow[(size_t)s * DINC] = y;
        crow[(size_t)s * DINC] = cum;
    }
#pragma unroll
    for (int n = 0; n < NSTC; ++n)
        hendT[((size_t)(bk * NCH + c) * NSTC + n) * DINC + d] = h[n];
    sumdT[(size_t)(bk * NCH + c) * DINC + d] = cum;
}

// ---------- 4b. scan2: thread=(d,n), serial over chunks. grid 96 x 256 ----------
__global__ __launch_bounds__(256) void scan2_k(float* __restrict__ hendT,
                                               const float* __restrict__ sumdT,
                                               const float* __restrict__ alog) {
    int gid = blockIdx.x * 256 + threadIdx.x;
    int d = gid % DINC;
    int n = (gid / DINC) % NSTC;
    int bk = gid / (DINC * NSTC);
    int k = bk & 3;
    float An2 = -__expf(alog[((size_t)(k * DINC + d)) * NSTC + n]) * LOG2E;
    float h = 0.f;
#pragma unroll 4
    for (int c = 0; c < NCH; ++c) {
        size_t idx = ((size_t)(bk * NCH + c) * NSTC + n) * DINC + d;
        float he = hendT[idx];
        float sd = sumdT[(size_t)(bk * NCH + c) * DINC + d];
        hendT[idx] = h;
        h = fmaf(fexp2(An2 * sd), h, he);
    }
}

// ---------- 4c. pass2: y += sum_n C*exp2(A2*cumd)*hpre, [l][d] rows. grid 448 x 256 ----------
__global__ __launch_bounds__(256) void pass2_k(const float* __restrict__ bcC,
                                               const float* __restrict__ alog,
                                               const float* __restrict__ hpreT,
                                               const float* __restrict__ cumdT,
                                               float* __restrict__ ysT) {
    __shared__ float sA2[DINC * 17];
    __shared__ float sH[DINC * 17];
    __shared__ float sC[LC * NSTC];
    int blk = blockIdx.x;
    int c = blk % NCH;
    int bk = blk / NCH;
    int k = bk & 3;
    int l0 = c * LC;
    int tid = threadIdx.x;
    const float* ap = alog + (size_t)k * DINC * NSTC;
    for (int f = tid; f < DINC * NSTC; f += 256) {
        int dq = f / NSTC, n = f % NSTC;
        sA2[dq * 17 + n] = -__expf(ap[f]) * LOG2E;
    }
    for (int f = tid; f < DINC * NSTC; f += 256) {
        int n = f / DINC, dq = f % DINC;
        sH[dq * 17 + n] = hpreT[((size_t)(bk * NCH + c) * NSTC + n) * DINC + dq];
    }
    const float* bC = bcC + ((size_t)bk * LL + l0) * NSTC;
    for (int f = tid; f < LC * NSTC; f += 256) sC[f] = bC[f];
    __syncthreads();
    for (int e = tid; e < LC * DINC; e += 256) {
        int li = e / DINC, d = e - DINC * (e / DINC);
        size_t gq = ((size_t)bk * LL + l0 + li) * DINC + d;
        float cd = cumdT[gq];
        float y = ysT[gq];
        const float* A = &sA2[d * 17];
        const float* Hp = &sH[d * 17];
        const float* Cp = &sC[li * NSTC];
#pragma unroll
        for (int n = 0; n < NSTC; ++n)
            y = fmaf(Hp[n] * fexp2(A[n] * cd), Cp[n], y);
        ysT[gq] = y;
    }
}

// ---------- 5. combine: elementwise over [pos][d] rows -> yt_T. grid 392 x 256 ----------
__global__ __launch_bounds__(256) void combine_k(const float* __restrict__ ysT,
                                                 const float* __restrict__ xscanT,
                                                 const float* __restrict__ dsv,
                                                 float* __restrict__ ytT) {
    __shared__ float sD[DINC];
    int blk = blockIdx.x;
    int p0 = (blk % 196) * 16;
    int b = blk / 196;
    int tid = threadIdx.x;
    if (tid < DINC)
        sD[tid] = dsv[tid] + dsv[DINC + tid] + dsv[2 * DINC + tid] + dsv[3 * DINC + tid];
    __syncthreads();
    size_t base = (size_t)b * KDIR * LL;
    for (int e = tid; e < 16 * DINC; e += 256) {
        int pi = e / DINC, d = e - DINC * (e / DINC);
        int pos = p0 + pi;
        int hh = pos / 56, w = pos - 56 * hh;
        int lt = w * 56 + hh;
        float y = ysT[(base + pos) * DINC + d]
                + ysT[(base + LL + lt) * DINC + d]
                + ysT[(base + 2 * LL + (LL - 1 - pos)) * DINC + d]
                + ysT[(base + 3 * LL + (LL - 1 - lt)) * DINC + d];
        float xv = xscanT[(base + pos) * DINC + d];  // k=0 slice = xconv at [pos][d]
        ytT[((size_t)b * LL + pos) * DINC + d] = fmaf(xv, sD[d], y);
    }
}

// ---------- 6. fused out_norm*silu(z) + out_proj + residual (reads yt_T) ----------
__global__ __launch_bounds__(256) void gemm2_k(const float* __restrict__ ytT,
                                               const float* __restrict__ g,
                                               const float* __restrict__ bt,
                                               const float* __restrict__ zs,
                                               const float* __restrict__ opw,
                                               const float* __restrict__ x,
                                               const float* __restrict__ sc1,
                                               float* __restrict__ vl) {
    __shared__ float xT[64 * 193];
    __shared__ float wT[96 * 52];
    __shared__ float mA[64], iA[64];
    int row0 = blockIdx.x * 64;
    int b = row0 / LL, pos0 = row0 % LL;
    for (int f = threadIdx.x; f < 64 * 48; f += 256) {
        int r = f / 48, cq = (f % 48) * 4;
        *(float4*)&xT[r * 193 + cq] = *(const float4*)&ytT[((size_t)(row0 + r)) * DINC + cq];
    }
    __syncthreads();
    if (threadIdx.x < 64) {
        float s = 0.f, q = 0.f;
        const float* xr = &xT[threadIdx.x * 193];
        for (int c = 0; c < 192; ++c) { float v = xr[c]; s += v; q = fmaf(v, v, q); }
        float m = s * (1.f / 192.f);
        mA[threadIdx.x] = m;
        iA[threadIdx.x] = rsqrtf(q * (1.f / 192.f) - m * m + EPSF);
    }
    __syncthreads();
    for (int e = threadIdx.x; e < 64 * 192; e += 256) {
        int row = e / 192, col = e - row * 192;
        float v = xT[row * 193 + col];
        float z = zs[(size_t)row0 * DINC + e];
        xT[row * 193 + col] = ((v - mA[row]) * iA[row] * g[col] + bt[col]) * z;
    }
    int tc = threadIdx.x & 15, tr = threadIdx.x >> 4;
    float acc[4][6] = {};
    for (int kc = 0; kc < 4; ++kc) {
        __syncthreads();
        for (int f = threadIdx.x; f < 96 * 12; f += 256) {
            int r = f / 12, kq = (f % 12) * 4;
            *(float4*)&wT[r * 52 + kq] = *(const float4*)&opw[(size_t)r * DINC + kc * 48 + kq];
        }
        __syncthreads();
        for (int k = 0; k < 48; ++k) {
            float xv[4], wv[6];
#pragma unroll
            for (int i = 0; i < 4; ++i) xv[i] = xT[(4 * tr + i) * 193 + kc * 48 + k];
#pragma unroll
            for (int j = 0; j < 6; ++j) wv[j] = wT[(tc + 16 * j) * 52 + k];
#pragma unroll
            for (int i = 0; i < 4; ++i)
#pragma unroll
                for (int j = 0; j < 6; ++j) acc[i][j] = fmaf(xv[i], wv[j], acc[i][j]);
        }
    }
#pragma unroll
    for (int i = 0; i < 4; ++i) {
        int pos = pos0 + 4 * tr + i;
#pragma unroll
        for (int j = 0; j < 6; ++j) {
            int col = tc + 16 * j;
            float v = fmaf(sc1[col], x[((size_t)b * DIMC + col) * LL + pos], acc[i][j]);
            vl[(size_t)(row0 + 4 * tr + i) * DIMC + col] = v;
        }
    }
}

// ---------- 7. LN2 + conv1x1(96->24) + BN + ReLU ----------
__global__ __launch_bounds__(256) void ln2conv1_k(const float* __restrict__ vl,
                                                  const float* __restrict__ g,
                                                  const float* __restrict__ bt,
                                                  const float* __restrict__ w1,
                                                  const float* __restrict__ g1,
                                                  const float* __restrict__ b1,
                                                  const float* __restrict__ m1,
                                                  const float* __restrict__ v1,
                                                  float* __restrict__ h1) {
    __shared__ float row[4][96];
    int wv = threadIdx.x >> 6, lane = threadIdx.x & 63;
    int pix = blockIdx.x * 4 + wv;
    const float* vr = vl + (size_t)pix * DIMC;
    float a0 = vr[lane];
    float a1 = (lane < 32) ? vr[64 + lane] : 0.f;
    float s = a0 + a1, q = a0 * a0 + a1 * a1;
    for (int o = 32; o; o >>= 1) { s += __shfl_xor(s, o, 64); q += __shfl_xor(q, o, 64); }
    float m = s * (1.f / 96.f);
    float inv = rsqrtf(q * (1.f / 96.f) - m * m + EPSF);
    row[wv][lane] = (a0 - m) * inv * g[lane] + bt[lane];
    if (lane < 32) row[wv][64 + lane] = (a1 - m) * inv * g[64 + lane] + bt[64 + lane];
    __syncthreads();
    if (lane < 24) {
        const float* wr = w1 + lane * 96;
        float acc = 0.f;
#pragma unroll 8
        for (int c = 0; c < 96; ++c) acc = fmaf(row[wv][c], wr[c], acc);
        float bn = (acc - m1[lane]) * rsqrtf(v1[lane] + EPSF) * g1[lane] + b1[lane];
        int b = pix / LL, pos = pix % LL;
        h1[((size_t)b * 24 + lane) * LL + pos] = fmaxf(bn, 0.f);
    }
}

// ---------- 8. conv3x3 (24->24) + BN + ReLU ----------
__global__ __launch_bounds__(256) void conv2_k(const float* __restrict__ h1,
                                               const float* __restrict__ w2,
                                               const float* __restrict__ g2,
                                               const float* __restrict__ b2,
                                               const float* __restrict__ m2,
                                               const float* __restrict__ v2,
                                               float* __restrict__ h2) {
    int i = blockIdx.x * 256 + threadIdx.x;
    int pos = i % LL, mo = (i / LL) % 24, b = i / (LL * 24);
    int hh = pos / WWD, ww = pos % WWD;
    float acc = 0.f;
    for (int c = 0; c < 24; ++c) {
        const float* src = h1 + ((size_t)b * 24 + c) * LL;
        const float* wk = w2 + ((size_t)(mo * 24 + c)) * 9;
#pragma unroll
        for (int ky = 0; ky < 3; ++ky) {
            int y = hh + ky - 1;
            if ((unsigned)y >= HH) continue;
#pragma unroll
            for (int kx = 0; kx < 3; ++kx) {
                int xq = ww + kx - 1;
                if ((unsigned)xq >= WWD) continue;
                acc = fmaf(wk[ky * 3 + kx], src[y * WWD + xq], acc);
            }
        }
    }
    float bn = (acc - m2[mo]) * rsqrtf(v2[mo] + EPSF) * g2[mo] + b2[mo];
    h2[i] = fmaxf(bn, 0.f);
}

// ---------- 9. conv1x1 (24->96) + BN ----------
__global__ __launch_bounds__(256) void conv3_k(const float* __restrict__ h2,
                                               const float* __restrict__ w3,
                                               const float* __restrict__ g3,
                                               const float* __restrict__ b3,
                                               const float* __restrict__ m3,
                                               const float* __restrict__ v3,
                                               float* __restrict__ h3) {
    int i = blockIdx.x * 256 + threadIdx.x;
    int pos = i % LL, c = (i / LL) % DIMC, b = i / (LL * DIMC);
    const float* wr = w3 + c * 24;
    float acc = 0.f;
#pragma unroll
    for (int mo = 0; mo < 24; ++mo)
        acc = fmaf(wr[mo], h2[((size_t)b * 24 + mo) * LL + pos], acc);
    h3[i] = (acc - m3[c]) * rsqrtf(v3[c] + EPSF) * g3[c] + b3[c];
}

// ---------- 10. SE pool ----------
__global__ __launch_bounds__(256) void pool_k(const float* __restrict__ h3,
                                              float* __restrict__ pooled) {
    int bc = blockIdx.x;
    const float* p = h3 + (size_t)bc * LL;
    float s = 0.f;
    for (int i = threadIdx.x; i < LL; i += 256) s += p[i];
    for (int o = 32; o; o >>= 1) s += __shfl_xor(s, o, 64);
    __shared__ float wsum[4];
    if ((threadIdx.x & 63) == 0) wsum[threadIdx.x >> 6] = s;
    __syncthreads();
    if (threadIdx.x == 0) pooled[bc] = (wsum[0] + wsum[1] + wsum[2] + wsum[3]) * (1.f / 3136.f);
}

// ---------- 11. SE MLP ----------
__global__ __launch_bounds__(128) void semlp_k(const float* __restrict__ pooled,
                                               const float* __restrict__ sw1,
                                               const float* __restrict__ sw2,
                                               float* __restrict__ sew) {
    __shared__ float pl[2][96];
    __shared__ float hid[2][24];
    for (int i = threadIdx.x; i < 192; i += 128) pl[i / 96][i % 96] = pooled[i];
    __syncthreads();
    if (threadIdx.x < 48) {
        int b = threadIdx.x / 24, mo = threadIdx.x % 24;
        float acc = 0.f;
        for (int c = 0; c < 96; ++c) acc = fmaf(pl[b][c], sw1[mo * 96 + c], acc);
        hid[b][mo] = fmaxf(acc, 0.f);
    }
    __syncthreads();
    for (int i = threadIdx.x; i < 192; i += 128) {
        int b = i / 96, c = i % 96;
        float acc = 0.f;
        for (int mo = 0; mo < 24; ++mo) acc = fmaf(hid[b][mo], sw2[c * 24 + mo], acc);
        sew[i] = 1.f / (1.f + __expf(-acc));
    }
}

// ---------- 12. final ----------
__global__ __launch_bounds__(256) void final_k(const float* __restrict__ h3,
                                               const float* __restrict__ sew,
                                               const float* __restrict__ vl,
                                               const float* __restrict__ sc2,
                                               float* __restrict__ out) {
    int i = blockIdx.x * 256 + threadIdx.x;
    int pos = i % LL, c = (i / LL) % DIMC, b = i / (LL * DIMC);
    out[i] = fmaf(h3[i], sew[b * DIMC + c],
                  sc2[c] * vl[((size_t)b * LL + pos) * DIMC + c]);
}

extern "C" void kernel_launch(void* const* d_in, const int* in_sizes, int n_in,
                              void* d_out, int out_size, void* d_ws, size_t ws_size,
                              hipStream_t stream) {
    const float* x    = (const float*)d_in[0];
    const float* n1g  = (const float*)d_in[1];
    const float* n1b  = (const float*)d_in[2];
    const float* ipw  = (const float*)d_in[3];
    const float* cw   = (const float*)d_in[4];
    const float* cb   = (const float*)d_in[5];
    const float* xpw  = (const float*)d_in[6];
    const float* dtw  = (const float*)d_in[7];
    const float* dtb  = (const float*)d_in[8];
    const float* alog = (const float*)d_in[9];
    const float* dsv  = (const float*)d_in[10];
    const float* ong  = (const float*)d_in[11];
    const float* onb  = (const float*)d_in[12];
    const float* opw  = (const float*)d_in[13];
    const float* sc1  = (const float*)d_in[14];
    const float* n2g  = (const float*)d_in[15];
    const float* n2b  = (const float*)d_in[16];
    const float* w1   = (const float*)d_in[17];
    const float* g1   = (const float*)d_in[18];
    const float* b1   = (const float*)d_in[19];
    const float* m1   = (const float*)d_in[20];
    const float* v1   = (const float*)d_in[21];
    const float* w2   = (const float*)d_in[22];
    const float* g2   = (const float*)d_in[23];
    const float* b2   = (const float*)d_in[24];
    const float* m2   = (const float*)d_in[25];
    const float* v2   = (const float*)d_in[26];
    const float* w3   = (const float*)d_in[27];
    const float* g3   = (const float*)d_in[28];
    const float* b3   = (const float*)d_in[29];
    const float* m3   = (const float*)d_in[30];
    const float* v3   = (const float*)d_in[31];
    const float* sw1  = (const float*)d_in[32];
    const float* sw2  = (const float*)d_in[33];
    const float* sc2  = (const float*)d_in[34];
    float* ws = (float*)d_ws;
    float* out = (float*)d_out;

    gemm1_k<<<dim3(NPIX / 64, 4), 256, 0, stream>>>(x, n1g, n1b, ipw,
                                                    ws + OFF_XCRAW, ws + OFF_ZS);
    dwconv_k<<<BB * DINC, 448, 0, stream>>>(ws + OFF_XCRAW, cw, cb, ws + OFF_XCONV);
    gemmx_k<<<NPIX / 64, 256, 0, stream>>>(ws + OFF_XCONV, xpw, ws + OFF_DTS,
                                           ws + OFF_BCB, ws + OFF_BCC, ws + OFF_XSCANT);

    pass1_k<<<BB * KDIR * 3 * NCH, 64, 0, stream>>>(
        ws + OFF_DTS, ws + OFF_BCB, ws + OFF_BCC, alog, dtw, dtb,
        ws + OFF_XSCANT, ws + OFF_HENDT, ws + OFF_SUMDT, ws + OFF_YS, ws + OFF_CUMD);
    scan2_k<<<(NCHAIN * NSTC) / 256, 256, 0, stream>>>(ws + OFF_HENDT, ws + OFF_SUMDT, alog);
    pass2_k<<<BB * KDIR * NCH, 256, 0, stream>>>(
        ws + OFF_BCC, alog, ws + OFF_HENDT, ws + OFF_CUMD, ws + OFF_YS);

    combine_k<<<BB * 196, 256, 0, stream>>>(ws + OFF_YS, ws + OFF_XSCANT, dsv, ws + OFF_YT);
    gemm2_k<<<NPIX / 64, 256, 0, stream>>>(ws + OFF_YT, ong, onb, ws + OFF_ZS, opw, x, sc1,
                                           ws + OFF_VL);
    ln2conv1_k<<<NPIX / 4, 256, 0, stream>>>(ws + OFF_VL, n2g, n2b, w1, g1, b1, m1, v1,
                                             ws + OFF_H1);
    conv2_k<<<(BB * 24 * LL) / 256, 256, 0, stream>>>(ws + OFF_H1, w2, g2, b2, m2, v2,
                                                      ws + OFF_H2);
    conv3_k<<<(BB * DIMC * LL) / 256, 256, 0, stream>>>(ws + OFF_H2, w3, g3, b3, m3, v3,
                                                        ws + OFF_H3);
    pool_k<<<BB * DIMC, 256, 0, stream>>>(ws + OFF_H3, ws + OFF_POOL);
    semlp_k<<<1, 128, 0, stream>>>(ws + OFF_POOL, sw1, sw2, ws + OFF_SEW);
    final_k<<<(BB * DIMC * LL) / 256, 256, 0, stream>>>(ws + OFF_H3, ws + OFF_SEW, ws + OFF_VL,
                                                        sc2, out);
    (void)in_sizes; (void)n_in; (void)out_size; (void)ws_size;
}

// Round 11
// 252.310 us; speedup vs baseline: 1.1422x; 1.0646x over previous
//
#include <hip/hip_runtime.h>
#include <math.h>

#define DIMC 96
#define DINC 192
#define NSTC 16
#define DTRC 6
#define KDIR 4
#define BB   2
#define HH   56
#define WWD  56
#define LL   3136
#define NPIX (BB*LL)           // 6272
#define EPSF 1e-5f
#define NCH  98                // chunks per chain
#define LC   32                // chunk length (98*32=3136)
#define NCHAIN (BB*KDIR*DINC)  // 1536
#define NCOLS 152              // 4*38

// ---------- workspace layout (float offsets) ----------
#define OFF_XCRAW  0u          // 1204224 (gemm1->dwconv)
#define OFF_XCONV  1204224u    // 1204224 (dwconv->gemmx)
#define OFF_ZS     2408448u    // 1204224 (gemm1->gemm2)
#define OFF_DTS    3612672u    // 150528
#define OFF_BCB    3763200u    // 401408
#define OFF_BCC    4164608u    // 401408
#define OFF_XSCANT 4566016u    // 4816896 [bk][l][d] (gemmx->pass1, gemm2 k0 slice)
#define OFF_CUMD   9382912u    // 4816896 (pass1->pass2)
#define OFF_YS     14199808u   // 4816896 (pass1->pass2 in-place ->gemm2)
#define OFF_HENDT  0u          // 2408448 reuses XCRAW+XCONV (dead after gemmx)
#define OFF_SUMDT  19016704u   // 150528 -> ends 19167232
// post-pass2 (CUMD dead):
#define OFF_VL     9382912u    // 602112
#define OFF_H1     9985024u    // 150528
#define OFF_H2     10135552u   // 150528
#define OFF_H3     10286080u   // 602112
#define OFF_POOL   10888192u   // 192
#define OFF_SEW    10888384u   // 192

__device__ __forceinline__ float siluf(float x) { return x / (1.f + __expf(-x)); }
__device__ __forceinline__ float softplusf(float x) {
    return fmaxf(x, 0.f) + __logf(1.f + __expf(-fabsf(x)));
}
__device__ __forceinline__ float fexp2(float x) {
#if __has_builtin(__builtin_amdgcn_exp2f)
    return __builtin_amdgcn_exp2f(x);
#else
    return exp2f(x);
#endif
}
#define LOG2E 1.44269504088896f

// ---------- 1. fused LN1 + in_proj GEMM. grid (98,4) x 256 ----------
__global__ __launch_bounds__(256) void gemm1_k(const float* __restrict__ x,
                                               const float* __restrict__ g,
                                               const float* __restrict__ bt,
                                               const float* __restrict__ W,
                                               float* __restrict__ xcr,
                                               float* __restrict__ zs) {
    __shared__ float xT[64 * 97];
    __shared__ float wT[96 * 100];
    __shared__ float mA[64], iA[64];
    int row0 = blockIdx.x * 64;
    int b = row0 / LL, pos0 = row0 % LL;
    int c0 = blockIdx.y * 96;
    for (int f = threadIdx.x; f < 96 * 16; f += 256) {
        int ch = f >> 4, po = (f & 15) * 4;
        float4 v = *(const float4*)&x[((size_t)b * DIMC + ch) * LL + pos0 + po];
        xT[(po + 0) * 97 + ch] = v.x; xT[(po + 1) * 97 + ch] = v.y;
        xT[(po + 2) * 97 + ch] = v.z; xT[(po + 3) * 97 + ch] = v.w;
    }
    for (int f = threadIdx.x; f < 96 * 24; f += 256) {
        int r = f / 24, kq = (f % 24) * 4;
        *(float4*)&wT[r * 100 + kq] = *(const float4*)&W[(size_t)(c0 + r) * DIMC + kq];
    }
    __syncthreads();
    if (threadIdx.x < 64) {
        float s = 0.f, q = 0.f;
        const float* xr = &xT[threadIdx.x * 97];
        for (int c = 0; c < 96; ++c) { float v = xr[c]; s += v; q = fmaf(v, v, q); }
        float m = s * (1.f / 96.f);
        mA[threadIdx.x] = m;
        iA[threadIdx.x] = rsqrtf(q * (1.f / 96.f) - m * m + EPSF);
    }
    __syncthreads();
    for (int e = threadIdx.x; e < 64 * 96; e += 256) {
        int row = e / 96, col = e - row * 96;
        float v = xT[row * 97 + col];
        xT[row * 97 + col] = (v - mA[row]) * iA[row] * g[col] + bt[col];
    }
    __syncthreads();
    int tc = threadIdx.x & 15, tr = threadIdx.x >> 4;
    float acc[4][6] = {};
    for (int k = 0; k < 96; ++k) {
        float xv[4], wv[6];
#pragma unroll
        for (int i = 0; i < 4; ++i) xv[i] = xT[(4 * tr + i) * 97 + k];
#pragma unroll
        for (int j = 0; j < 6; ++j) wv[j] = wT[(tc + 16 * j) * 100 + k];
#pragma unroll
        for (int i = 0; i < 4; ++i)
#pragma unroll
            for (int j = 0; j < 6; ++j) acc[i][j] = fmaf(xv[i], wv[j], acc[i][j]);
    }
    int pos = pos0 + 4 * tr;
    if (c0 < DINC) {
#pragma unroll
        for (int j = 0; j < 6; ++j) {
            int col = c0 + tc + 16 * j;
            float4 v = make_float4(acc[0][j], acc[1][j], acc[2][j], acc[3][j]);
            *(float4*)&xcr[((size_t)b * DINC + col) * LL + pos] = v;
        }
    } else {
#pragma unroll
        for (int i = 0; i < 4; ++i)
#pragma unroll
            for (int j = 0; j < 6; ++j) {
                int zc = c0 - DINC + tc + 16 * j;
                zs[(size_t)(row0 + 4 * tr + i) * DINC + zc] = siluf(acc[i][j]);
            }
    }
}

// ---------- 2. depthwise 3x3 conv + silu -> xconv ----------
__global__ __launch_bounds__(448) void dwconv_k(const float* __restrict__ xcr,
                                                const float* __restrict__ cw,
                                                const float* __restrict__ cb,
                                                float* __restrict__ xconv) {
    __shared__ float P[56 * 57];
    int bd = blockIdx.x;
    int d = bd % DINC;
    size_t base = (size_t)bd * LL;
    for (int t = threadIdx.x; t < LL; t += 448)
        P[(t / 56) * 57 + (t % 56)] = xcr[base + t];
    float wk[9];
#pragma unroll
    for (int q = 0; q < 9; ++q) wk[q] = cw[d * 9 + q];
    float bias = cb[d];
    __syncthreads();
    for (int t = threadIdx.x; t < LL; t += 448) {
        int h = t / 56, w = t % 56;
        float acc = bias;
#pragma unroll
        for (int ky = 0; ky < 3; ++ky) {
            int y = h + ky - 1;
            if ((unsigned)y >= 56u) continue;
#pragma unroll
            for (int kx = 0; kx < 3; ++kx) {
                int xq = w + kx - 1;
                if ((unsigned)xq >= 56u) continue;
                acc = fmaf(wk[ky * 3 + kx], P[y * 57 + xq], acc);
            }
        }
        xconv[base + t] = siluf(acc);
    }
}

// ---------- 3. x_proj GEMM + xscan_T emit. grid 98 x 256 ----------
__global__ __launch_bounds__(256) void gemmx_k(const float* __restrict__ xconv,
                                               const float* __restrict__ xpw,
                                               float* __restrict__ dts,
                                               float* __restrict__ bcB,
                                               float* __restrict__ bcC,
                                               float* __restrict__ xscanT) {
    __shared__ float xT[64 * 49];
    __shared__ float wT[NCOLS * 52];
    int row0 = blockIdx.x * 64;
    int b = row0 / LL, pos0 = row0 % LL;
    int tc = threadIdx.x & 15, tr = threadIdx.x >> 4;
    float acc[4][10] = {};
    for (int kc = 0; kc < 4; ++kc) {
        if (kc) __syncthreads();
        for (int f = threadIdx.x; f < 48 * 16; f += 256) {
            int dd = f >> 4, po = (f & 15) * 4;
            float4 v = *(const float4*)&xconv[((size_t)b * DINC + kc * 48 + dd) * LL + pos0 + po];
            xT[(po + 0) * 49 + dd] = v.x; xT[(po + 1) * 49 + dd] = v.y;
            xT[(po + 2) * 49 + dd] = v.z; xT[(po + 3) * 49 + dd] = v.w;
        }
        for (int f = threadIdx.x; f < NCOLS * 12; f += 256) {
            int r = f / 12, kq = (f % 12) * 4;
            *(float4*)&wT[r * 52 + kq] = *(const float4*)&xpw[(size_t)r * DINC + kc * 48 + kq];
        }
        __syncthreads();
        for (int k = 0; k < 48; ++k) {
            float xv[4], wv[10];
#pragma unroll
            for (int i = 0; i < 4; ++i) xv[i] = xT[(4 * tr + i) * 49 + k];
#pragma unroll
            for (int j = 0; j < 10; ++j) {
                int c = tc + 16 * j;
                wv[j] = (c < NCOLS) ? wT[c * 52 + k] : 0.f;
            }
#pragma unroll
            for (int i = 0; i < 4; ++i)
#pragma unroll
                for (int j = 0; j < 10; ++j) acc[i][j] = fmaf(xv[i], wv[j], acc[i][j]);
        }
        for (int f = threadIdx.x; f < 64 * 48; f += 256) {
            int i = f / 48, dd = f - 48 * (f / 48);
            float v = xT[i * 49 + dd];
            int pos = pos0 + i;
            int hh = pos / 56, w = pos - 56 * hh;
            int lt = w * 56 + hh;
            size_t bb = (size_t)b * KDIR;
            int col = kc * 48 + dd;
            xscanT[((bb + 0) * LL + pos) * DINC + col] = v;
            xscanT[((bb + 1) * LL + lt) * DINC + col] = v;
            xscanT[((bb + 2) * LL + (LL - 1 - pos)) * DINC + col] = v;
            xscanT[((bb + 3) * LL + (LL - 1 - lt)) * DINC + col] = v;
        }
    }
#pragma unroll
    for (int i = 0; i < 4; ++i) {
        int pos = pos0 + 4 * tr + i;
        int h = pos / 56, w = pos - 56 * h;
        int lt = w * 56 + h;
#pragma unroll
        for (int j = 0; j < 10; ++j) {
            int c = tc + 16 * j;
            if (c >= NCOLS) continue;
            int k = c / 38, idx = c - 38 * k;
            int l = (k == 0) ? pos : (k == 1) ? lt : (k == 2) ? (LL - 1 - pos) : (LL - 1 - lt);
            size_t rb = (size_t)(b * KDIR + k) * LL + l;
            float v = acc[i][j];
            if (idx < DTRC)    dts[rb * DTRC + idx] = v;
            else if (idx < 22) bcB[rb * NSTC + (idx - 6)] = v;
            else               bcC[rb * NSTC + (idx - 22)] = v;
        }
    }
}

// ---------- 4a. pass1: d-per-thread local scan. grid 8*3*98 = 2352 x 64 ----------
__global__ __launch_bounds__(64) void pass1_k(const float* __restrict__ dts,
                                              const float* __restrict__ bcB,
                                              const float* __restrict__ bcC,
                                              const float* __restrict__ alog,
                                              const float* __restrict__ dtw,
                                              const float* __restrict__ dtb,
                                              const float* __restrict__ xscanT,
                                              float* __restrict__ hendT,
                                              float* __restrict__ sumdT,
                                              float* __restrict__ ysT,
                                              float* __restrict__ cumdT) {
    __shared__ float sdt[LC * 7];
    __shared__ float sB[LC * 16];
    __shared__ float sC[LC * 16];
    int blk = blockIdx.x;
    int c = blk % NCH;
    int dtile = (blk / NCH) % 3;
    int bk = blk / (NCH * 3);
    int k = bk & 3;
    int l0 = c * LC;
    int t = threadIdx.x;
    int d = dtile * 64 + t;
    const float* dsrc = dts + ((size_t)bk * LL + l0) * DTRC;
    for (int f = t; f < LC * DTRC; f += 64) sdt[(f / DTRC) * 7 + (f % DTRC)] = dsrc[f];
    const float* bB = bcB + ((size_t)bk * LL + l0) * NSTC;
    const float* bC = bcC + ((size_t)bk * LL + l0) * NSTC;
    for (int f = t; f < LC * NSTC; f += 64) { sB[f] = bB[f]; sC[f] = bC[f]; }
    float wr[DTRC];
    {
        const float* wp = dtw + ((size_t)k * DINC + d) * DTRC;
#pragma unroll
        for (int r = 0; r < DTRC; ++r) wr[r] = wp[r];
    }
    float bias = dtb[k * DINC + d];
    float An2[NSTC];
    {
        const float* ap = alog + ((size_t)(k * DINC + d)) * NSTC;
#pragma unroll
        for (int n = 0; n < NSTC; ++n) An2[n] = -__expf(ap[n]) * LOG2E;
    }
    __syncthreads();
    float h[NSTC];
#pragma unroll
    for (int n = 0; n < NSTC; ++n) h[n] = 0.f;
    float cum = 0.f;
    const float* xrow = xscanT + ((size_t)bk * LL + l0) * DINC + d;
    float* yrow = ysT + ((size_t)bk * LL + l0) * DINC + d;
    float* crow = cumdT + ((size_t)bk * LL + l0) * DINC + d;
#pragma unroll 8
    for (int s = 0; s < LC; ++s) {
        float acc = bias;
#pragma unroll
        for (int r = 0; r < DTRC; ++r) acc = fmaf(wr[r], sdt[s * 7 + r], acc);
        float dv = softplusf(acc);
        float xv = xrow[(size_t)s * DINC];
        cum += dv;
        float dx = dv * xv;
        const float4* B4 = (const float4*)&sB[s * 16];
        const float4* C4 = (const float4*)&sC[s * 16];
        float y = 0.f;
#pragma unroll
        for (int nq = 0; nq < 4; ++nq) {
            float4 Bv = B4[nq], Cv = C4[nq];
            float e0 = fexp2(An2[nq * 4 + 0] * dv);
            h[nq * 4 + 0] = fmaf(e0, h[nq * 4 + 0], dx * Bv.x);
            y = fmaf(h[nq * 4 + 0], Cv.x, y);
            float e1 = fexp2(An2[nq * 4 + 1] * dv);
            h[nq * 4 + 1] = fmaf(e1, h[nq * 4 + 1], dx * Bv.y);
            y = fmaf(h[nq * 4 + 1], Cv.y, y);
            float e2 = fexp2(An2[nq * 4 + 2] * dv);
            h[nq * 4 + 2] = fmaf(e2, h[nq * 4 + 2], dx * Bv.z);
            y = fmaf(h[nq * 4 + 2], Cv.z, y);
            float e3 = fexp2(An2[nq * 4 + 3] * dv);
            h[nq * 4 + 3] = fmaf(e3, h[nq * 4 + 3], dx * Bv.w);
            y = fmaf(h[nq * 4 + 3], Cv.w, y);
        }
        yrow[(size_t)s * DINC] = y;
        crow[(size_t)s * DINC] = cum;
    }
#pragma unroll
    for (int n = 0; n < NSTC; ++n)
        hendT[((size_t)(bk * NCH + c) * NSTC + n) * DINC + d] = h[n];
    sumdT[(size_t)(bk * NCH + c) * DINC + d] = cum;
}

// ---------- 4b. scan2: thread=(d,n), serial over chunks. grid 96 x 256 ----------
__global__ __launch_bounds__(256) void scan2_k(float* __restrict__ hendT,
                                               const float* __restrict__ sumdT,
                                               const float* __restrict__ alog) {
    int gid = blockIdx.x * 256 + threadIdx.x;
    int d = gid % DINC;
    int n = (gid / DINC) % NSTC;
    int bk = gid / (DINC * NSTC);
    int k = bk & 3;
    float An2 = -__expf(alog[((size_t)(k * DINC + d)) * NSTC + n]) * LOG2E;
    float h = 0.f;
#pragma unroll 4
    for (int c = 0; c < NCH; ++c) {
        size_t idx = ((size_t)(bk * NCH + c) * NSTC + n) * DINC + d;
        float he = hendT[idx];
        float sd = sumdT[(size_t)(bk * NCH + c) * DINC + d];
        hendT[idx] = h;
        h = fmaf(fexp2(An2 * sd), h, he);
    }
}

// ---------- 4c. pass2: y += sum_n C*exp2(A2*cumd)*hpre. grid 784 x 256 ----------
__global__ __launch_bounds__(256) void pass2_k(const float* __restrict__ bcC,
                                               const float* __restrict__ alog,
                                               const float* __restrict__ hpreT,
                                               const float* __restrict__ cumdT,
                                               float* __restrict__ ysT) {
    __shared__ float sA2[DINC * 17];
    __shared__ float sH[DINC * 17];
    __shared__ float sC[LC * NSTC];
    int blk = blockIdx.x;
    int c = blk % NCH;
    int bk = blk / NCH;
    int k = bk & 3;
    int l0 = c * LC;
    int tid = threadIdx.x;
    const float* ap = alog + (size_t)k * DINC * NSTC;
    for (int f = tid; f < DINC * NSTC; f += 256) {
        int dq = f / NSTC, n = f % NSTC;
        sA2[dq * 17 + n] = -__expf(ap[f]) * LOG2E;
    }
    for (int f = tid; f < DINC * NSTC; f += 256) {
        int n = f / DINC, dq = f % DINC;
        sH[dq * 17 + n] = hpreT[((size_t)(bk * NCH + c) * NSTC + n) * DINC + dq];
    }
    const float* bC = bcC + ((size_t)bk * LL + l0) * NSTC;
    for (int f = tid; f < LC * NSTC; f += 256) sC[f] = bC[f];
    __syncthreads();
    for (int e = tid; e < LC * DINC; e += 256) {
        int li = e / DINC, d = e - DINC * (e / DINC);
        size_t gq = ((size_t)bk * LL + l0 + li) * DINC + d;
        float cd = cumdT[gq];
        float y = ysT[gq];
        const float* A = &sA2[d * 17];
        const float* Hp = &sH[d * 17];
        const float* Cp = &sC[li * NSTC];
#pragma unroll
        for (int n = 0; n < NSTC; ++n)
            y = fmaf(Hp[n] * fexp2(A[n] * cd), Cp[n], y);
        ysT[gq] = y;
    }
}

// ---------- 5. fused combine + out_norm*silu(z) + out_proj + residual ----------
__global__ __launch_bounds__(256) void gemm2_k(const float* __restrict__ ysT,
                                               const float* __restrict__ xscanT,
                                               const float* __restrict__ dsv,
                                               const float* __restrict__ g,
                                               const float* __restrict__ bt,
                                               const float* __restrict__ zs,
                                               const float* __restrict__ opw,
                                               const float* __restrict__ x,
                                               const float* __restrict__ sc1,
                                               float* __restrict__ vl) {
    __shared__ float xT[64 * 193];
    __shared__ float wT[96 * 52];
    __shared__ float mA[64], iA[64];
    __shared__ float sD[DINC];
    int row0 = blockIdx.x * 64;
    int b = row0 / LL, pos0 = row0 % LL;
    if (threadIdx.x < DINC)
        sD[threadIdx.x] = dsv[threadIdx.x] + dsv[DINC + threadIdx.x] +
                          dsv[2 * DINC + threadIdx.x] + dsv[3 * DINC + threadIdx.x];
    __syncthreads();
    size_t base = (size_t)b * KDIR * LL;
    for (int f = threadIdx.x; f < 64 * DINC; f += 256) {
        int r = f / DINC, d = f - DINC * (f / DINC);
        int pos = pos0 + r;
        int hh = pos / 56, w = pos - 56 * hh;
        int lt = w * 56 + hh;
        float y = ysT[(base + pos) * DINC + d]
                + ysT[(base + LL + lt) * DINC + d]
                + ysT[(base + 2 * LL + (LL - 1 - pos)) * DINC + d]
                + ysT[(base + 3 * LL + (LL - 1 - lt)) * DINC + d];
        float xv = xscanT[(base + pos) * DINC + d];  // k=0 slice
        xT[r * 193 + d] = fmaf(xv, sD[d], y);
    }
    __syncthreads();
    if (threadIdx.x < 64) {
        float s = 0.f, q = 0.f;
        const float* xr = &xT[threadIdx.x * 193];
        for (int c = 0; c < 192; ++c) { float v = xr[c]; s += v; q = fmaf(v, v, q); }
        float m = s * (1.f / 192.f);
        mA[threadIdx.x] = m;
        iA[threadIdx.x] = rsqrtf(q * (1.f / 192.f) - m * m + EPSF);
    }
    __syncthreads();
    for (int e = threadIdx.x; e < 64 * 192; e += 256) {
        int row = e / 192, col = e - row * 192;
        float v = xT[row * 193 + col];
        float z = zs[(size_t)row0 * DINC + e];
        xT[row * 193 + col] = ((v - mA[row]) * iA[row] * g[col] + bt[col]) * z;
    }
    int tc = threadIdx.x & 15, tr = threadIdx.x >> 4;
    float acc[4][6] = {};
    for (int kc = 0; kc < 4; ++kc) {
        __syncthreads();
        for (int f = threadIdx.x; f < 96 * 12; f += 256) {
            int r = f / 12, kq = (f % 12) * 4;
            *(float4*)&wT[r * 52 + kq] = *(const float4*)&opw[(size_t)r * DINC + kc * 48 + kq];
        }
        __syncthreads();
        for (int k = 0; k < 48; ++k) {
            float xv[4], wv[6];
#pragma unroll
            for (int i = 0; i < 4; ++i) xv[i] = xT[(4 * tr + i) * 193 + kc * 48 + k];
#pragma unroll
            for (int j = 0; j < 6; ++j) wv[j] = wT[(tc + 16 * j) * 52 + k];
#pragma unroll
            for (int i = 0; i < 4; ++i)
#pragma unroll
                for (int j = 0; j < 6; ++j) acc[i][j] = fmaf(xv[i], wv[j], acc[i][j]);
        }
    }
#pragma unroll
    for (int i = 0; i < 4; ++i) {
        int pos = pos0 + 4 * tr + i;
#pragma unroll
        for (int j = 0; j < 6; ++j) {
            int col = tc + 16 * j;
            float v = fmaf(sc1[col], x[((size_t)b * DIMC + col) * LL + pos], acc[i][j]);
            vl[(size_t)(row0 + 4 * tr + i) * DIMC + col] = v;
        }
    }
}

// ---------- 6. LN2 + conv1x1(96->24) + BN + ReLU ----------
__global__ __launch_bounds__(256) void ln2conv1_k(const float* __restrict__ vl,
                                                  const float* __restrict__ g,
                                                  const float* __restrict__ bt,
                                                  const float* __restrict__ w1,
                                                  const float* __restrict__ g1,
                                                  const float* __restrict__ b1,
                                                  const float* __restrict__ m1,
                                                  const float* __restrict__ v1,
                                                  float* __restrict__ h1) {
    __shared__ float row[4][96];
    int wv = threadIdx.x >> 6, lane = threadIdx.x & 63;
    int pix = blockIdx.x * 4 + wv;
    const float* vr = vl + (size_t)pix * DIMC;
    float a0 = vr[lane];
    float a1 = (lane < 32) ? vr[64 + lane] : 0.f;
    float s = a0 + a1, q = a0 * a0 + a1 * a1;
    for (int o = 32; o; o >>= 1) { s += __shfl_xor(s, o, 64); q += __shfl_xor(q, o, 64); }
    float m = s * (1.f / 96.f);
    float inv = rsqrtf(q * (1.f / 96.f) - m * m + EPSF);
    row[wv][lane] = (a0 - m) * inv * g[lane] + bt[lane];
    if (lane < 32) row[wv][64 + lane] = (a1 - m) * inv * g[64 + lane] + bt[64 + lane];
    __syncthreads();
    if (lane < 24) {
        const float* wr = w1 + lane * 96;
        float acc = 0.f;
#pragma unroll 8
        for (int c = 0; c < 96; ++c) acc = fmaf(row[wv][c], wr[c], acc);
        float bn = (acc - m1[lane]) * rsqrtf(v1[lane] + EPSF) * g1[lane] + b1[lane];
        int b = pix / LL, pos = pix % LL;
        h1[((size_t)b * 24 + lane) * LL + pos] = fmaxf(bn, 0.f);
    }
}

// ---------- 7. conv3x3 (24->24) + BN + ReLU ----------
__global__ __launch_bounds__(256) void conv2_k(const float* __restrict__ h1,
                                               const float* __restrict__ w2,
                                               const float* __restrict__ g2,
                                               const float* __restrict__ b2,
                                               const float* __restrict__ m2,
                                               const float* __restrict__ v2,
                                               float* __restrict__ h2) {
    int i = blockIdx.x * 256 + threadIdx.x;
    int pos = i % LL, mo = (i / LL) % 24, b = i / (LL * 24);
    int hh = pos / WWD, ww = pos % WWD;
    float acc = 0.f;
    for (int c = 0; c < 24; ++c) {
        const float* src = h1 + ((size_t)b * 24 + c) * LL;
        const float* wk = w2 + ((size_t)(mo * 24 + c)) * 9;
#pragma unroll
        for (int ky = 0; ky < 3; ++ky) {
            int y = hh + ky - 1;
            if ((unsigned)y >= HH) continue;
#pragma unroll
            for (int kx = 0; kx < 3; ++kx) {
                int xq = ww + kx - 1;
                if ((unsigned)xq >= WWD) continue;
                acc = fmaf(wk[ky * 3 + kx], src[y * WWD + xq], acc);
            }
        }
    }
    float bn = (acc - m2[mo]) * rsqrtf(v2[mo] + EPSF) * g2[mo] + b2[mo];
    h2[i] = fmaxf(bn, 0.f);
}

// ---------- 8. conv1x1 (24->96) + BN ----------
__global__ __launch_bounds__(256) void conv3_k(const float* __restrict__ h2,
                                               const float* __restrict__ w3,
                                               const float* __restrict__ g3,
                                               const float* __restrict__ b3,
                                               const float* __restrict__ m3,
                                               const float* __restrict__ v3,
                                               float* __restrict__ h3) {
    int i = blockIdx.x * 256 + threadIdx.x;
    int pos = i % LL, c = (i / LL) % DIMC, b = i / (LL * DIMC);
    const float* wr = w3 + c * 24;
    float acc = 0.f;
#pragma unroll
    for (int mo = 0; mo < 24; ++mo)
        acc = fmaf(wr[mo], h2[((size_t)b * 24 + mo) * LL + pos], acc);
    h3[i] = (acc - m3[c]) * rsqrtf(v3[c] + EPSF) * g3[c] + b3[c];
}

// ---------- 9. SE pool ----------
__global__ __launch_bounds__(256) void pool_k(const float* __restrict__ h3,
                                              float* __restrict__ pooled) {
    int bc = blockIdx.x;
    const float* p = h3 + (size_t)bc * LL;
    float s = 0.f;
    for (int i = threadIdx.x; i < LL; i += 256) s += p[i];
    for (int o = 32; o; o >>= 1) s += __shfl_xor(s, o, 64);
    __shared__ float wsum[4];
    if ((threadIdx.x & 63) == 0) wsum[threadIdx.x >> 6] = s;
    __syncthreads();
    if (threadIdx.x == 0) pooled[bc] = (wsum[0] + wsum[1] + wsum[2] + wsum[3]) * (1.f / 3136.f);
}

// ---------- 10. SE MLP ----------
__global__ __launch_bounds__(128) void semlp_k(const float* __restrict__ pooled,
                                               const float* __restrict__ sw1,
                                               const float* __restrict__ sw2,
                                               float* __restrict__ sew) {
    __shared__ float pl[2][96];
    __shared__ float hid[2][24];
    for (int i = threadIdx.x; i < 192; i += 128) pl[i / 96][i % 96] = pooled[i];
    __syncthreads();
    if (threadIdx.x < 48) {
        int b = threadIdx.x / 24, mo = threadIdx.x % 24;
        float acc = 0.f;
        for (int c = 0; c < 96; ++c) acc = fmaf(pl[b][c], sw1[mo * 96 + c], acc);
        hid[b][mo] = fmaxf(acc, 0.f);
    }
    __syncthreads();
    for (int i = threadIdx.x; i < 192; i += 128) {
        int b = i / 96, c = i % 96;
        float acc = 0.f;
        for (int mo = 0; mo < 24; ++mo) acc = fmaf(hid[b][mo], sw2[c * 24 + mo], acc);
        sew[i] = 1.f / (1.f + __expf(-acc));
    }
}

// ---------- 11. final ----------
__global__ __launch_bounds__(256) void final_k(const float* __restrict__ h3,
                                               const float* __restrict__ sew,
                                               const float* __restrict__ vl,
                                               const float* __restrict__ sc2,
                                               float* __restrict__ out) {
    int i = blockIdx.x * 256 + threadIdx.x;
    int pos = i % LL, c = (i / LL) % DIMC, b = i / (LL * DIMC);
    out[i] = fmaf(h3[i], sew[b * DIMC + c],
                  sc2[c] * vl[((size_t)b * LL + pos) * DIMC + c]);
}

extern "C" void kernel_launch(void* const* d_in, const int* in_sizes, int n_in,
                              void* d_out, int out_size, void* d_ws, size_t ws_size,
                              hipStream_t stream) {
    const float* x    = (const float*)d_in[0];
    const float* n1g  = (const float*)d_in[1];
    const float* n1b  = (const float*)d_in[2];
    const float* ipw  = (const float*)d_in[3];
    const float* cw   = (const float*)d_in[4];
    const float* cb   = (const float*)d_in[5];
    const float* xpw  = (const float*)d_in[6];
    const float* dtw  = (const float*)d_in[7];
    const float* dtb  = (const float*)d_in[8];
    const float* alog = (const float*)d_in[9];
    const float* dsv  = (const float*)d_in[10];
    const float* ong  = (const float*)d_in[11];
    const float* onb  = (const float*)d_in[12];
    const float* opw  = (const float*)d_in[13];
    const float* sc1  = (const float*)d_in[14];
    const float* n2g  = (const float*)d_in[15];
    const float* n2b  = (const float*)d_in[16];
    const float* w1   = (const float*)d_in[17];
    const float* g1   = (const float*)d_in[18];
    const float* b1   = (const float*)d_in[19];
    const float* m1   = (const float*)d_in[20];
    const float* v1   = (const float*)d_in[21];
    const float* w2   = (const float*)d_in[22];
    const float* g2   = (const float*)d_in[23];
    const float* b2   = (const float*)d_in[24];
    const float* m2   = (const float*)d_in[25];
    const float* v2   = (const float*)d_in[26];
    const float* w3   = (const float*)d_in[27];
    const float* g3   = (const float*)d_in[28];
    const float* b3   = (const float*)d_in[29];
    const float* m3   = (const float*)d_in[30];
    const float* v3   = (const float*)d_in[31];
    const float* sw1  = (const float*)d_in[32];
    const float* sw2  = (const float*)d_in[33];
    const float* sc2  = (const float*)d_in[34];
    float* ws = (float*)d_ws;
    float* out = (float*)d_out;

    gemm1_k<<<dim3(NPIX / 64, 4), 256, 0, stream>>>(x, n1g, n1b, ipw,
                                                    ws + OFF_XCRAW, ws + OFF_ZS);
    dwconv_k<<<BB * DINC, 448, 0, stream>>>(ws + OFF_XCRAW, cw, cb, ws + OFF_XCONV);
    gemmx_k<<<NPIX / 64, 256, 0, stream>>>(ws + OFF_XCONV, xpw, ws + OFF_DTS,
                                           ws + OFF_BCB, ws + OFF_BCC, ws + OFF_XSCANT);

    pass1_k<<<BB * KDIR * 3 * NCH, 64, 0, stream>>>(
        ws + OFF_DTS, ws + OFF_BCB, ws + OFF_BCC, alog, dtw, dtb,
        ws + OFF_XSCANT, ws + OFF_HENDT, ws + OFF_SUMDT, ws + OFF_YS, ws + OFF_CUMD);
    scan2_k<<<(NCHAIN * NSTC) / 256, 256, 0, stream>>>(ws + OFF_HENDT, ws + OFF_SUMDT, alog);
    pass2_k<<<BB * KDIR * NCH, 256, 0, stream>>>(
        ws + OFF_BCC, alog, ws + OFF_HENDT, ws + OFF_CUMD, ws + OFF_YS);

    gemm2_k<<<NPIX / 64, 256, 0, stream>>>(ws + OFF_YS, ws + OFF_XSCANT, dsv,
                                           ong, onb, ws + OFF_ZS, opw, x, sc1, ws + OFF_VL);
    ln2conv1_k<<<NPIX / 4, 256, 0, stream>>>(ws + OFF_VL, n2g, n2b, w1, g1, b1, m1, v1,
                                             ws + OFF_H1);
    conv2_k<<<(BB * 24 * LL) / 256, 256, 0, stream>>>(ws + OFF_H1, w2, g2, b2, m2, v2,
                                                      ws + OFF_H2);
    conv3_k<<<(BB * DIMC * LL) / 256, 256, 0, stream>>>(ws + OFF_H2, w3, g3, b3, m3, v3,
                                                        ws + OFF_H3);
    pool_k<<<BB * DIMC, 256, 0, stream>>>(ws + OFF_H3, ws + OFF_POOL);
    semlp_k<<<1, 128, 0, stream>>>(ws + OFF_POOL, sw1, sw2, ws + OFF_SEW);
    final_k<<<(BB * DIMC * LL) / 256, 256, 0, stream>>>(ws + OFF_H3, ws + OFF_SEW, ws + OFF_VL,
                                                        sc2, out);
    (void)in_sizes; (void)n_in; (void)out_size; (void)ws_size;
}

// Round 12
// 244.140 us; speedup vs baseline: 1.1805x; 1.0335x over previous
//
#include <hip/hip_runtime.h>
#include <math.h>

#define DIMC 96
#define DINC 192
#define NSTC 16
#define DTRC 6
#define KDIR 4
#define BB   2
#define HH   56
#define WWD  56
#define LL   3136
#define NPIX (BB*LL)           // 6272
#define EPSF 1e-5f
#define NCH  98                // chunks per chain
#define LC   32                // chunk length (98*32=3136)
#define NCHAIN (BB*KDIR*DINC)  // 1536
#define NCOLS 152              // 4*38

// ---------- workspace layout (float offsets) ----------
#define OFF_XCRAW  0u          // 1204224 (gemm1->dwconv)
#define OFF_XCONV  1204224u    // 1204224 (dwconv->gemmx)
#define OFF_ZS     2408448u    // 1204224 (gemm1->gemm2)
#define OFF_DTS    3612672u    // 150528
#define OFF_BCB    3763200u    // 401408
#define OFF_BCC    4164608u    // 401408
#define OFF_XSCANT 4566016u    // 2408448 [b*2+slice][l][d] (2 slices; k>=2 read reversed)
#define OFF_CUMD   6974464u    // 4816896 (pass1->pass2)
#define OFF_YS     11791360u   // 4816896 (pass1->pass2 in-place ->gemm2)
#define OFF_HENDT  0u          // 2408448 reuses XCRAW+XCONV (dead after gemmx); 8*98*16*192
#define OFF_SUMDT  16608256u   // 150528 -> ends 16758784
// post-pass2 (CUMD dead):
#define OFF_VL     6974464u    // 602112
#define OFF_H1     7576576u    // 150528
#define OFF_H2     7727104u    // 150528
#define OFF_H3     7877632u    // 602112
#define OFF_POOL   8479744u    // 192
#define OFF_SEW    8479936u    // 192

__device__ __forceinline__ float siluf(float x) { return x / (1.f + __expf(-x)); }
__device__ __forceinline__ float softplusf(float x) {
    return fmaxf(x, 0.f) + __logf(1.f + __expf(-fabsf(x)));
}
__device__ __forceinline__ float fexp2(float x) {
#if __has_builtin(__builtin_amdgcn_exp2f)
    return __builtin_amdgcn_exp2f(x);
#else
    return exp2f(x);
#endif
}
#define LOG2E 1.44269504088896f

// ---------- 1. fused LN1 + in_proj GEMM. grid (98,4) x 256 ----------
__global__ __launch_bounds__(256) void gemm1_k(const float* __restrict__ x,
                                               const float* __restrict__ g,
                                               const float* __restrict__ bt,
                                               const float* __restrict__ W,
                                               float* __restrict__ xcr,
                                               float* __restrict__ zs) {
    __shared__ float xT[64 * 97];
    __shared__ float wT[96 * 100];
    __shared__ float mA[64], iA[64];
    int row0 = blockIdx.x * 64;
    int b = row0 / LL, pos0 = row0 % LL;
    int c0 = blockIdx.y * 96;
    for (int f = threadIdx.x; f < 96 * 16; f += 256) {
        int ch = f >> 4, po = (f & 15) * 4;
        float4 v = *(const float4*)&x[((size_t)b * DIMC + ch) * LL + pos0 + po];
        xT[(po + 0) * 97 + ch] = v.x; xT[(po + 1) * 97 + ch] = v.y;
        xT[(po + 2) * 97 + ch] = v.z; xT[(po + 3) * 97 + ch] = v.w;
    }
    for (int f = threadIdx.x; f < 96 * 24; f += 256) {
        int r = f / 24, kq = (f % 24) * 4;
        *(float4*)&wT[r * 100 + kq] = *(const float4*)&W[(size_t)(c0 + r) * DIMC + kq];
    }
    __syncthreads();
    if (threadIdx.x < 64) {
        float s = 0.f, q = 0.f;
        const float* xr = &xT[threadIdx.x * 97];
        for (int c = 0; c < 96; ++c) { float v = xr[c]; s += v; q = fmaf(v, v, q); }
        float m = s * (1.f / 96.f);
        mA[threadIdx.x] = m;
        iA[threadIdx.x] = rsqrtf(q * (1.f / 96.f) - m * m + EPSF);
    }
    __syncthreads();
    for (int e = threadIdx.x; e < 64 * 96; e += 256) {
        int row = e / 96, col = e - row * 96;
        float v = xT[row * 97 + col];
        xT[row * 97 + col] = (v - mA[row]) * iA[row] * g[col] + bt[col];
    }
    __syncthreads();
    int tc = threadIdx.x & 15, tr = threadIdx.x >> 4;
    float acc[4][6] = {};
    for (int k = 0; k < 96; ++k) {
        float xv[4], wv[6];
#pragma unroll
        for (int i = 0; i < 4; ++i) xv[i] = xT[(4 * tr + i) * 97 + k];
#pragma unroll
        for (int j = 0; j < 6; ++j) wv[j] = wT[(tc + 16 * j) * 100 + k];
#pragma unroll
        for (int i = 0; i < 4; ++i)
#pragma unroll
            for (int j = 0; j < 6; ++j) acc[i][j] = fmaf(xv[i], wv[j], acc[i][j]);
    }
    int pos = pos0 + 4 * tr;
    if (c0 < DINC) {
#pragma unroll
        for (int j = 0; j < 6; ++j) {
            int col = c0 + tc + 16 * j;
            float4 v = make_float4(acc[0][j], acc[1][j], acc[2][j], acc[3][j]);
            *(float4*)&xcr[((size_t)b * DINC + col) * LL + pos] = v;
        }
    } else {
#pragma unroll
        for (int i = 0; i < 4; ++i)
#pragma unroll
            for (int j = 0; j < 6; ++j) {
                int zc = c0 - DINC + tc + 16 * j;
                zs[(size_t)(row0 + 4 * tr + i) * DINC + zc] = siluf(acc[i][j]);
            }
    }
}

// ---------- 2. depthwise 3x3 conv + silu -> xconv ----------
__global__ __launch_bounds__(448) void dwconv_k(const float* __restrict__ xcr,
                                                const float* __restrict__ cw,
                                                const float* __restrict__ cb,
                                                float* __restrict__ xconv) {
    __shared__ float P[56 * 57];
    int bd = blockIdx.x;
    int d = bd % DINC;
    size_t base = (size_t)bd * LL;
    for (int t = threadIdx.x; t < LL; t += 448)
        P[(t / 56) * 57 + (t % 56)] = xcr[base + t];
    float wk[9];
#pragma unroll
    for (int q = 0; q < 9; ++q) wk[q] = cw[d * 9 + q];
    float bias = cb[d];
    __syncthreads();
    for (int t = threadIdx.x; t < LL; t += 448) {
        int h = t / 56, w = t % 56;
        float acc = bias;
#pragma unroll
        for (int ky = 0; ky < 3; ++ky) {
            int y = h + ky - 1;
            if ((unsigned)y >= 56u) continue;
#pragma unroll
            for (int kx = 0; kx < 3; ++kx) {
                int xq = w + kx - 1;
                if ((unsigned)xq >= 56u) continue;
                acc = fmaf(wk[ky * 3 + kx], P[y * 57 + xq], acc);
            }
        }
        xconv[base + t] = siluf(acc);
    }
}

// ---------- 3. x_proj GEMM + 2-slice xscan_T emit. grid 392 x 256 (M=16) ----------
__global__ __launch_bounds__(256) void gemmx_k(const float* __restrict__ xconv,
                                               const float* __restrict__ xpw,
                                               float* __restrict__ dts,
                                               float* __restrict__ bcB,
                                               float* __restrict__ bcC,
                                               float* __restrict__ xscanT) {
    __shared__ float xT[16 * 49];
    __shared__ float wT[NCOLS * 52];
    int row0 = blockIdx.x * 16;
    int b = row0 / LL, pos0 = row0 % LL;
    int tc = threadIdx.x & 15, tr = threadIdx.x >> 4;
    float acc[10] = {};
    for (int kc = 0; kc < 4; ++kc) {
        if (kc) __syncthreads();
        // stage x tile: 48 d-rows x 16 pos, transposed into [pos][d]
        for (int f = threadIdx.x; f < 48 * 4; f += 256) {
            int dd = f >> 2, po = (f & 3) * 4;
            float4 v = *(const float4*)&xconv[((size_t)b * DINC + kc * 48 + dd) * LL + pos0 + po];
            xT[(po + 0) * 49 + dd] = v.x; xT[(po + 1) * 49 + dd] = v.y;
            xT[(po + 2) * 49 + dd] = v.z; xT[(po + 3) * 49 + dd] = v.w;
        }
        for (int f = threadIdx.x; f < NCOLS * 12; f += 256) {
            int r = f / 12, kq = (f % 12) * 4;
            *(float4*)&wT[r * 52 + kq] = *(const float4*)&xpw[(size_t)r * DINC + kc * 48 + kq];
        }
        __syncthreads();
#pragma unroll 4
        for (int k = 0; k < 48; ++k) {
            float xv = xT[tr * 49 + k];
            float wv[10];
#pragma unroll
            for (int j = 0; j < 10; ++j) {
                int c = tc + 16 * j;
                wv[j] = (c < NCOLS) ? wT[c * 52 + k] : 0.f;
            }
#pragma unroll
            for (int j = 0; j < 10; ++j) acc[j] = fmaf(xv, wv[j], acc[j]);
        }
        // emit 2 xscan_T slices for this 48-d band
        for (int f = threadIdx.x; f < 16 * 48; f += 256) {
            int i = f / 48, dd = f - 48 * (f / 48);
            float v = xT[i * 49 + dd];
            int pos = pos0 + i;
            int hh = pos / 56, w = pos - 56 * hh;
            int lt = w * 56 + hh;
            size_t bb = (size_t)b * 2;
            int col = kc * 48 + dd;
            xscanT[((bb + 0) * LL + pos) * DINC + col] = v;
            xscanT[((bb + 1) * LL + lt) * DINC + col] = v;
        }
    }
    // scatter epilogue: row tr (one pos), cols tc+16j
    {
        int pos = pos0 + tr;
        int h = pos / 56, w = pos - 56 * h;
        int lt = w * 56 + h;
#pragma unroll
        for (int j = 0; j < 10; ++j) {
            int c = tc + 16 * j;
            if (c >= NCOLS) continue;
            int k = c / 38, idx = c - 38 * k;
            int l = (k == 0) ? pos : (k == 1) ? lt : (k == 2) ? (LL - 1 - pos) : (LL - 1 - lt);
            size_t rb = (size_t)(b * KDIR + k) * LL + l;
            float v = acc[j];
            if (idx < DTRC)    dts[rb * DTRC + idx] = v;
            else if (idx < 22) bcB[rb * NSTC + (idx - 6)] = v;
            else               bcC[rb * NSTC + (idx - 22)] = v;
        }
    }
}

// ---------- 4a. pass1: d-per-thread local scan. grid 8*3*98 = 2352 x 64 ----------
__global__ __launch_bounds__(64) void pass1_k(const float* __restrict__ dts,
                                              const float* __restrict__ bcB,
                                              const float* __restrict__ bcC,
                                              const float* __restrict__ alog,
                                              const float* __restrict__ dtw,
                                              const float* __restrict__ dtb,
                                              const float* __restrict__ xscanT,
                                              float* __restrict__ hendT,
                                              float* __restrict__ sumdT,
                                              float* __restrict__ ysT,
                                              float* __restrict__ cumdT) {
    __shared__ float sdt[LC * 7];
    __shared__ float sB[LC * 16];
    __shared__ float sC[LC * 16];
    int blk = blockIdx.x;
    int c = blk % NCH;
    int dtile = (blk / NCH) % 3;
    int bk = blk / (NCH * 3);
    int k = bk & 3, b = bk >> 2;
    int l0 = c * LC;
    int t = threadIdx.x;
    int d = dtile * 64 + t;
    const float* dsrc = dts + ((size_t)bk * LL + l0) * DTRC;
    for (int f = t; f < LC * DTRC; f += 64) sdt[(f / DTRC) * 7 + (f % DTRC)] = dsrc[f];
    const float* bB = bcB + ((size_t)bk * LL + l0) * NSTC;
    const float* bC = bcC + ((size_t)bk * LL + l0) * NSTC;
    for (int f = t; f < LC * NSTC; f += 64) { sB[f] = bB[f]; sC[f] = bC[f]; }
    float wr[DTRC];
    {
        const float* wp = dtw + ((size_t)k * DINC + d) * DTRC;
#pragma unroll
        for (int r = 0; r < DTRC; ++r) wr[r] = wp[r];
    }
    float bias = dtb[k * DINC + d];
    float An2[NSTC];
    {
        const float* ap = alog + ((size_t)(k * DINC + d)) * NSTC;
#pragma unroll
        for (int n = 0; n < NSTC; ++n) An2[n] = -__expf(ap[n]) * LOG2E;
    }
    __syncthreads();
    float h[NSTC];
#pragma unroll
    for (int n = 0; n < NSTC; ++n) h[n] = 0.f;
    float cum = 0.f;
    bool rev = (k >= 2);
    const float* xbase = xscanT + ((size_t)(b * 2 + (k & 1)) * LL) * DINC + d;
    int xi0 = rev ? (LL - 1 - l0) : l0;
    float* yrow = ysT + ((size_t)bk * LL + l0) * DINC + d;
    float* crow = cumdT + ((size_t)bk * LL + l0) * DINC + d;
#pragma unroll 8
    for (int s = 0; s < LC; ++s) {
        float acc = bias;
#pragma unroll
        for (int r = 0; r < DTRC; ++r) acc = fmaf(wr[r], sdt[s * 7 + r], acc);
        float dv = softplusf(acc);
        float xv = xbase[(size_t)(rev ? (xi0 - s) : (xi0 + s)) * DINC];
        cum += dv;
        float dx = dv * xv;
        const float4* B4 = (const float4*)&sB[s * 16];
        const float4* C4 = (const float4*)&sC[s * 16];
        float y = 0.f;
#pragma unroll
        for (int nq = 0; nq < 4; ++nq) {
            float4 Bv = B4[nq], Cv = C4[nq];
            float e0 = fexp2(An2[nq * 4 + 0] * dv);
            h[nq * 4 + 0] = fmaf(e0, h[nq * 4 + 0], dx * Bv.x);
            y = fmaf(h[nq * 4 + 0], Cv.x, y);
            float e1 = fexp2(An2[nq * 4 + 1] * dv);
            h[nq * 4 + 1] = fmaf(e1, h[nq * 4 + 1], dx * Bv.y);
            y = fmaf(h[nq * 4 + 1], Cv.y, y);
            float e2 = fexp2(An2[nq * 4 + 2] * dv);
            h[nq * 4 + 2] = fmaf(e2, h[nq * 4 + 2], dx * Bv.z);
            y = fmaf(h[nq * 4 + 2], Cv.z, y);
            float e3 = fexp2(An2[nq * 4 + 3] * dv);
            h[nq * 4 + 3] = fmaf(e3, h[nq * 4 + 3], dx * Bv.w);
            y = fmaf(h[nq * 4 + 3], Cv.w, y);
        }
        yrow[(size_t)s * DINC] = y;
        crow[(size_t)s * DINC] = cum;
    }
#pragma unroll
    for (int n = 0; n < NSTC; ++n)
        hendT[((size_t)(bk * NCH + c) * NSTC + n) * DINC + d] = h[n];
    sumdT[(size_t)(bk * NCH + c) * DINC + d] = cum;
}

// ---------- 4b. scan2: thread=(d,n), serial over chunks. grid 96 x 256 ----------
__global__ __launch_bounds__(256) void scan2_k(float* __restrict__ hendT,
                                               const float* __restrict__ sumdT,
                                               const float* __restrict__ alog) {
    int gid = blockIdx.x * 256 + threadIdx.x;
    int d = gid % DINC;
    int n = (gid / DINC) % NSTC;
    int bk = gid / (DINC * NSTC);
    int k = bk & 3;
    float An2 = -__expf(alog[((size_t)(k * DINC + d)) * NSTC + n]) * LOG2E;
    float h = 0.f;
#pragma unroll 4
    for (int c = 0; c < NCH; ++c) {
        size_t idx = ((size_t)(bk * NCH + c) * NSTC + n) * DINC + d;
        float he = hendT[idx];
        float sd = sumdT[(size_t)(bk * NCH + c) * DINC + d];
        hendT[idx] = h;
        h = fmaf(fexp2(An2 * sd), h, he);
    }
}

// ---------- 4c. pass2: y += sum_n C*exp2(A2*cumd)*hpre. grid 784 x 256 ----------
__global__ __launch_bounds__(256) void pass2_k(const float* __restrict__ bcC,
                                               const float* __restrict__ alog,
                                               const float* __restrict__ hpreT,
                                               const float* __restrict__ cumdT,
                                               float* __restrict__ ysT) {
    __shared__ float sA2[DINC * 17];
    __shared__ float sH[DINC * 17];
    __shared__ float sC[LC * NSTC];
    int blk = blockIdx.x;
    int c = blk % NCH;
    int bk = blk / NCH;
    int k = bk & 3;
    int l0 = c * LC;
    int tid = threadIdx.x;
    const float* ap = alog + (size_t)k * DINC * NSTC;
    for (int f = tid; f < DINC * NSTC; f += 256) {
        int dq = f / NSTC, n = f % NSTC;
        sA2[dq * 17 + n] = -__expf(ap[f]) * LOG2E;
    }
    for (int f = tid; f < DINC * NSTC; f += 256) {
        int n = f / DINC, dq = f % DINC;
        sH[dq * 17 + n] = hpreT[((size_t)(bk * NCH + c) * NSTC + n) * DINC + dq];
    }
    const float* bC = bcC + ((size_t)bk * LL + l0) * NSTC;
    for (int f = tid; f < LC * NSTC; f += 256) sC[f] = bC[f];
    __syncthreads();
    for (int e = tid; e < LC * DINC; e += 256) {
        int li = e / DINC, d = e - DINC * (e / DINC);
        size_t gq = ((size_t)bk * LL + l0 + li) * DINC + d;
        float cd = cumdT[gq];
        float y = ysT[gq];
        const float* A = &sA2[d * 17];
        const float* Hp = &sH[d * 17];
        const float* Cp = &sC[li * NSTC];
#pragma unroll
        for (int n = 0; n < NSTC; ++n)
            y = fmaf(Hp[n] * fexp2(A[n] * cd), Cp[n], y);
        ysT[gq] = y;
    }
}

// ---------- 5. fused combine + out_norm*silu(z) + out_proj + residual ----------
__global__ __launch_bounds__(256) void gemm2_k(const float* __restrict__ ysT,
                                               const float* __restrict__ xscanT,
                                               const float* __restrict__ dsv,
                                               const float* __restrict__ g,
                                               const float* __restrict__ bt,
                                               const float* __restrict__ zs,
                                               const float* __restrict__ opw,
                                               const float* __restrict__ x,
                                               const float* __restrict__ sc1,
                                               float* __restrict__ vl) {
    __shared__ float xT[64 * 193];
    __shared__ float wT[96 * 52];
    __shared__ float mA[64], iA[64];
    __shared__ float sD[DINC];
    int row0 = blockIdx.x * 64;
    int b = row0 / LL, pos0 = row0 % LL;
    if (threadIdx.x < DINC)
        sD[threadIdx.x] = dsv[threadIdx.x] + dsv[DINC + threadIdx.x] +
                          dsv[2 * DINC + threadIdx.x] + dsv[3 * DINC + threadIdx.x];
    __syncthreads();
    size_t base = (size_t)b * KDIR * LL;
    size_t xbase = (size_t)b * 2 * LL;
    for (int f = threadIdx.x; f < 64 * DINC; f += 256) {
        int r = f / DINC, d = f - DINC * (f / DINC);
        int pos = pos0 + r;
        int hh = pos / 56, w = pos - 56 * hh;
        int lt = w * 56 + hh;
        float y = ysT[(base + pos) * DINC + d]
                + ysT[(base + LL + lt) * DINC + d]
                + ysT[(base + 2 * LL + (LL - 1 - pos)) * DINC + d]
                + ysT[(base + 3 * LL + (LL - 1 - lt)) * DINC + d];
        float xv = xscanT[(xbase + pos) * DINC + d];  // slice 0 = xconv at [pos][d]
        xT[r * 193 + d] = fmaf(xv, sD[d], y);
    }
    __syncthreads();
    if (threadIdx.x < 64) {
        float s = 0.f, q = 0.f;
        const float* xr = &xT[threadIdx.x * 193];
        for (int c = 0; c < 192; ++c) { float v = xr[c]; s += v; q = fmaf(v, v, q); }
        float m = s * (1.f / 192.f);
        mA[threadIdx.x] = m;
        iA[threadIdx.x] = rsqrtf(q * (1.f / 192.f) - m * m + EPSF);
    }
    __syncthreads();
    for (int e = threadIdx.x; e < 64 * 192; e += 256) {
        int row = e / 192, col = e - row * 192;
        float v = xT[row * 193 + col];
        float z = zs[(size_t)row0 * DINC + e];
        xT[row * 193 + col] = ((v - mA[row]) * iA[row] * g[col] + bt[col]) * z;
    }
    int tc = threadIdx.x & 15, tr = threadIdx.x >> 4;
    float acc[4][6] = {};
    for (int kc = 0; kc < 4; ++kc) {
        __syncthreads();
        for (int f = threadIdx.x; f < 96 * 12; f += 256) {
            int r = f / 12, kq = (f % 12) * 4;
            *(float4*)&wT[r * 52 + kq] = *(const float4*)&opw[(size_t)r * DINC + kc * 48 + kq];
        }
        __syncthreads();
        for (int k = 0; k < 48; ++k) {
            float xv[4], wv[6];
#pragma unroll
            for (int i = 0; i < 4; ++i) xv[i] = xT[(4 * tr + i) * 193 + kc * 48 + k];
#pragma unroll
            for (int j = 0; j < 6; ++j) wv[j] = wT[(tc + 16 * j) * 52 + k];
#pragma unroll
            for (int i = 0; i < 4; ++i)
#pragma unroll
                for (int j = 0; j < 6; ++j) acc[i][j] = fmaf(xv[i], wv[j], acc[i][j]);
        }
    }
#pragma unroll
    for (int i = 0; i < 4; ++i) {
        int pos = pos0 + 4 * tr + i;
#pragma unroll
        for (int j = 0; j < 6; ++j) {
            int col = tc + 16 * j;
            float v = fmaf(sc1[col], x[((size_t)b * DIMC + col) * LL + pos], acc[i][j]);
            vl[(size_t)(row0 + 4 * tr + i) * DIMC + col] = v;
        }
    }
}

// ---------- 6. LN2 + conv1x1(96->24) + BN + ReLU ----------
__global__ __launch_bounds__(256) void ln2conv1_k(const float* __restrict__ vl,
                                                  const float* __restrict__ g,
                                                  const float* __restrict__ bt,
                                                  const float* __restrict__ w1,
                                                  const float* __restrict__ g1,
                                                  const float* __restrict__ b1,
                                                  const float* __restrict__ m1,
                                                  const float* __restrict__ v1,
                                                  float* __restrict__ h1) {
    __shared__ float row[4][96];
    int wv = threadIdx.x >> 6, lane = threadIdx.x & 63;
    int pix = blockIdx.x * 4 + wv;
    const float* vr = vl + (size_t)pix * DIMC;
    float a0 = vr[lane];
    float a1 = (lane < 32) ? vr[64 + lane] : 0.f;
    float s = a0 + a1, q = a0 * a0 + a1 * a1;
    for (int o = 32; o; o >>= 1) { s += __shfl_xor(s, o, 64); q += __shfl_xor(q, o, 64); }
    float m = s * (1.f / 96.f);
    float inv = rsqrtf(q * (1.f / 96.f) - m * m + EPSF);
    row[wv][lane] = (a0 - m) * inv * g[lane] + bt[lane];
    if (lane < 32) row[wv][64 + lane] = (a1 - m) * inv * g[64 + lane] + bt[64 + lane];
    __syncthreads();
    if (lane < 24) {
        const float* wr = w1 + lane * 96;
        float acc = 0.f;
#pragma unroll 8
        for (int c = 0; c < 96; ++c) acc = fmaf(row[wv][c], wr[c], acc);
        float bn = (acc - m1[lane]) * rsqrtf(v1[lane] + EPSF) * g1[lane] + b1[lane];
        int b = pix / LL, pos = pix % LL;
        h1[((size_t)b * 24 + lane) * LL + pos] = fmaxf(bn, 0.f);
    }
}

// ---------- 7. conv3x3 (24->24) + BN + ReLU ----------
__global__ __launch_bounds__(256) void conv2_k(const float* __restrict__ h1,
                                               const float* __restrict__ w2,
                                               const float* __restrict__ g2,
                                               const float* __restrict__ b2,
                                               const float* __restrict__ m2,
                                               const float* __restrict__ v2,
                                               float* __restrict__ h2) {
    int i = blockIdx.x * 256 + threadIdx.x;
    int pos = i % LL, mo = (i / LL) % 24, b = i / (LL * 24);
    int hh = pos / WWD, ww = pos % WWD;
    float acc = 0.f;
    for (int c = 0; c < 24; ++c) {
        const float* src = h1 + ((size_t)b * 24 + c) * LL;
        const float* wk = w2 + ((size_t)(mo * 24 + c)) * 9;
#pragma unroll
        for (int ky = 0; ky < 3; ++ky) {
            int y = hh + ky - 1;
            if ((unsigned)y >= HH) continue;
#pragma unroll
            for (int kx = 0; kx < 3; ++kx) {
                int xq = ww + kx - 1;
                if ((unsigned)xq >= WWD) continue;
                acc = fmaf(wk[ky * 3 + kx], src[y * WWD + xq], acc);
            }
        }
    }
    float bn = (acc - m2[mo]) * rsqrtf(v2[mo] + EPSF) * g2[mo] + b2[mo];
    h2[i] = fmaxf(bn, 0.f);
}

// ---------- 8. conv1x1 (24->96) + BN ----------
__global__ __launch_bounds__(256) void conv3_k(const float* __restrict__ h2,
                                               const float* __restrict__ w3,
                                               const float* __restrict__ g3,
                                               const float* __restrict__ b3,
                                               const float* __restrict__ m3,
                                               const float* __restrict__ v3,
                                               float* __restrict__ h3) {
    int i = blockIdx.x * 256 + threadIdx.x;
    int pos = i % LL, c = (i / LL) % DIMC, b = i / (LL * DIMC);
    const float* wr = w3 + c * 24;
    float acc = 0.f;
#pragma unroll
    for (int mo = 0; mo < 24; ++mo)
        acc = fmaf(wr[mo], h2[((size_t)b * 24 + mo) * LL + pos], acc);
    h3[i] = (acc - m3[c]) * rsqrtf(v3[c] + EPSF) * g3[c] + b3[c];
}

// ---------- 9. SE pool ----------
__global__ __launch_bounds__(256) void pool_k(const float* __restrict__ h3,
                                              float* __restrict__ pooled) {
    int bc = blockIdx.x;
    const float* p = h3 + (size_t)bc * LL;
    float s = 0.f;
    for (int i = threadIdx.x; i < LL; i += 256) s += p[i];
    for (int o = 32; o; o >>= 1) s += __shfl_xor(s, o, 64);
    __shared__ float wsum[4];
    if ((threadIdx.x & 63) == 0) wsum[threadIdx.x >> 6] = s;
    __syncthreads();
    if (threadIdx.x == 0) pooled[bc] = (wsum[0] + wsum[1] + wsum[2] + wsum[3]) * (1.f / 3136.f);
}

// ---------- 10. SE MLP ----------
__global__ __launch_bounds__(128) void semlp_k(const float* __restrict__ pooled,
                                               const float* __restrict__ sw1,
                                               const float* __restrict__ sw2,
                                               float* __restrict__ sew) {
    __shared__ float pl[2][96];
    __shared__ float hid[2][24];
    for (int i = threadIdx.x; i < 192; i += 128) pl[i / 96][i % 96] = pooled[i];
    __syncthreads();
    if (threadIdx.x < 48) {
        int b = threadIdx.x / 24, mo = threadIdx.x % 24;
        float acc = 0.f;
        for (int c = 0; c < 96; ++c) acc = fmaf(pl[b][c], sw1[mo * 96 + c], acc);
        hid[b][mo] = fmaxf(acc, 0.f);
    }
    __syncthreads();
    for (int i = threadIdx.x; i < 192; i += 128) {
        int b = i / 96, c = i % 96;
        float acc = 0.f;
        for (int mo = 0; mo < 24; ++mo) acc = fmaf(hid[b][mo], sw2[c * 24 + mo], acc);
        sew[i] = 1.f / (1.f + __expf(-acc));
    }
}

// ---------- 11. final ----------
__global__ __launch_bounds__(256) void final_k(const float* __restrict__ h3,
                                               const float* __restrict__ sew,
                                               const float* __restrict__ vl,
                                               const float* __restrict__ sc2,
                                               float* __restrict__ out) {
    int i = blockIdx.x * 256 + threadIdx.x;
    int pos = i % LL, c = (i / LL) % DIMC, b = i / (LL * DIMC);
    out[i] = fmaf(h3[i], sew[b * DIMC + c],
                  sc2[c] * vl[((size_t)b * LL + pos) * DIMC + c]);
}

extern "C" void kernel_launch(void* const* d_in, const int* in_sizes, int n_in,
                              void* d_out, int out_size, void* d_ws, size_t ws_size,
                              hipStream_t stream) {
    const float* x    = (const float*)d_in[0];
    const float* n1g  = (const float*)d_in[1];
    const float* n1b  = (const float*)d_in[2];
    const float* ipw  = (const float*)d_in[3];
    const float* cw   = (const float*)d_in[4];
    const float* cb   = (const float*)d_in[5];
    const float* xpw  = (const float*)d_in[6];
    const float* dtw  = (const float*)d_in[7];
    const float* dtb  = (const float*)d_in[8];
    const float* alog = (const float*)d_in[9];
    const float* dsv  = (const float*)d_in[10];
    const float* ong  = (const float*)d_in[11];
    const float* onb  = (const float*)d_in[12];
    const float* opw  = (const float*)d_in[13];
    const float* sc1  = (const float*)d_in[14];
    const float* n2g  = (const float*)d_in[15];
    const float* n2b  = (const float*)d_in[16];
    const float* w1   = (const float*)d_in[17];
    const float* g1   = (const float*)d_in[18];
    const float* b1   = (const float*)d_in[19];
    const float* m1   = (const float*)d_in[20];
    const float* v1   = (const float*)d_in[21];
    const float* w2   = (const float*)d_in[22];
    const float* g2   = (const float*)d_in[23];
    const float* b2   = (const float*)d_in[24];
    const float* m2   = (const float*)d_in[25];
    const float* v2   = (const float*)d_in[26];
    const float* w3   = (const float*)d_in[27];
    const float* g3   = (const float*)d_in[28];
    const float* b3   = (const float*)d_in[29];
    const float* m3   = (const float*)d_in[30];
    const float* v3   = (const float*)d_in[31];
    const float* sw1  = (const float*)d_in[32];
    const float* sw2  = (const float*)d_in[33];
    const float* sc2  = (const float*)d_in[34];
    float* ws = (float*)d_ws;
    float* out = (float*)d_out;

    gemm1_k<<<dim3(NPIX / 64, 4), 256, 0, stream>>>(x, n1g, n1b, ipw,
                                                    ws + OFF_XCRAW, ws + OFF_ZS);
    dwconv_k<<<BB * DINC, 448, 0, stream>>>(ws + OFF_XCRAW, cw, cb, ws + OFF_XCONV);
    gemmx_k<<<NPIX / 16, 256, 0, stream>>>(ws + OFF_XCONV, xpw, ws + OFF_DTS,
                                           ws + OFF_BCB, ws + OFF_BCC, ws + OFF_XSCANT);

    pass1_k<<<BB * KDIR * 3 * NCH, 64, 0, stream>>>(
        ws + OFF_DTS, ws + OFF_BCB, ws + OFF_BCC, alog, dtw, dtb,
        ws + OFF_XSCANT, ws + OFF_HENDT, ws + OFF_SUMDT, ws + OFF_YS, ws + OFF_CUMD);
    scan2_k<<<(NCHAIN * NSTC) / 256, 256, 0, stream>>>(ws + OFF_HENDT, ws + OFF_SUMDT, alog);
    pass2_k<<<BB * KDIR * NCH, 256, 0, stream>>>(
        ws + OFF_BCC, alog, ws + OFF_HENDT, ws + OFF_CUMD, ws + OFF_YS);

    gemm2_k<<<NPIX / 64, 256, 0, stream>>>(ws + OFF_YS, ws + OFF_XSCANT, dsv,
                                           ong, onb, ws + OFF_ZS, opw, x, sc1, ws + OFF_VL);
    ln2conv1_k<<<NPIX / 4, 256, 0, stream>>>(ws + OFF_VL, n2g, n2b, w1, g1, b1, m1, v1,
                                             ws + OFF_H1);
    conv2_k<<<(BB * 24 * LL) / 256, 256, 0, stream>>>(ws + OFF_H1, w2, g2, b2, m2, v2,
                                                      ws + OFF_H2);
    conv3_k<<<(BB * DIMC * LL) / 256, 256, 0, stream>>>(ws + OFF_H2, w3, g3, b3, m3, v3,
                                                        ws + OFF_H3);
    pool_k<<<BB * DIMC, 256, 0, stream>>>(ws + OFF_H3, ws + OFF_POOL);
    semlp_k<<<1, 128, 0, stream>>>(ws + OFF_POOL, sw1, sw2, ws + OFF_SEW);
    final_k<<<(BB * DIMC * LL) / 256, 256, 0, stream>>>(ws + OFF_H3, ws + OFF_SEW, ws + OFF_VL,
                                                        sc2, out);
    (void)in_sizes; (void)n_in; (void)out_size; (void)ws_size;
}

// Round 13
// 218.501 us; speedup vs baseline: 1.3190x; 1.1173x over previous
//
#include <hip/hip_runtime.h>
#include <math.h>

#define DIMC 96
#define DINC 192
#define NSTC 16
#define DTRC 6
#define KDIR 4
#define BB   2
#define HH   56
#define WWD  56
#define LL   3136
#define NPIX (BB*LL)           // 6272
#define EPSF 1e-5f
#define NCH  98                // chunks per chain
#define LC   32                // chunk length (98*32=3136)
#define NCHAIN (BB*KDIR*DINC)  // 1536
#define NCOLS 152              // 4*38

// ---------- workspace layout (float offsets) ----------
#define OFF_XCRAW  0u          // 1204224 (gemm1->dwconv)
#define OFF_XCONV  1204224u    // 1204224 (dwconv->gemmx)
#define OFF_ZS     2408448u    // 1204224 (gemm1->gemm2)
#define OFF_DTS    3612672u    // 150528
#define OFF_BCB    3763200u    // 401408
#define OFF_BCC    4164608u    // 401408
#define OFF_XSCANT 4566016u    // 2408448 [b*2+slice][l][d] (2 slices; k>=2 read reversed)
#define OFF_CUMD   6974464u    // 4816896 (pass1->pass2)
#define OFF_YS     11791360u   // 4816896 (pass1->pass2 in-place ->gemm2)
#define OFF_HENDT  0u          // 2408448 reuses XCRAW+XCONV (dead after gemmx); 8*98*16*192
#define OFF_SUMDT  16608256u   // 150528 -> ends 16758784
// post-pass2 (CUMD dead):
#define OFF_VL     6974464u    // 602112
#define OFF_H1     7576576u    // 150528
#define OFF_H2     7727104u    // 150528
#define OFF_H3     7877632u    // 602112
#define OFF_POOL   8479744u    // 192
#define OFF_SEW    8479936u    // 192

__device__ __forceinline__ float siluf(float x) { return x / (1.f + __expf(-x)); }
__device__ __forceinline__ float softplusf(float x) {
    return fmaxf(x, 0.f) + __logf(1.f + __expf(-fabsf(x)));
}
__device__ __forceinline__ float fexp2(float x) {
#if __has_builtin(__builtin_amdgcn_exp2f)
    return __builtin_amdgcn_exp2f(x);
#else
    return exp2f(x);
#endif
}
#define LOG2E 1.44269504088896f

// ---------- 1. fused LN1 + in_proj GEMM. grid (98,4) x 256 ----------
__global__ __launch_bounds__(256) void gemm1_k(const float* __restrict__ x,
                                               const float* __restrict__ g,
                                               const float* __restrict__ bt,
                                               const float* __restrict__ W,
                                               float* __restrict__ xcr,
                                               float* __restrict__ zs) {
    __shared__ float xT[64 * 97];
    __shared__ float wT[96 * 100];
    __shared__ float mA[64], iA[64];
    int row0 = blockIdx.x * 64;
    int b = row0 / LL, pos0 = row0 % LL;
    int c0 = blockIdx.y * 96;
    for (int f = threadIdx.x; f < 96 * 16; f += 256) {
        int ch = f >> 4, po = (f & 15) * 4;
        float4 v = *(const float4*)&x[((size_t)b * DIMC + ch) * LL + pos0 + po];
        xT[(po + 0) * 97 + ch] = v.x; xT[(po + 1) * 97 + ch] = v.y;
        xT[(po + 2) * 97 + ch] = v.z; xT[(po + 3) * 97 + ch] = v.w;
    }
    for (int f = threadIdx.x; f < 96 * 24; f += 256) {
        int r = f / 24, kq = (f % 24) * 4;
        *(float4*)&wT[r * 100 + kq] = *(const float4*)&W[(size_t)(c0 + r) * DIMC + kq];
    }
    __syncthreads();
    if (threadIdx.x < 64) {
        float s = 0.f, q = 0.f;
        const float* xr = &xT[threadIdx.x * 97];
        for (int c = 0; c < 96; ++c) { float v = xr[c]; s += v; q = fmaf(v, v, q); }
        float m = s * (1.f / 96.f);
        mA[threadIdx.x] = m;
        iA[threadIdx.x] = rsqrtf(q * (1.f / 96.f) - m * m + EPSF);
    }
    __syncthreads();
    for (int e = threadIdx.x; e < 64 * 96; e += 256) {
        int row = e / 96, col = e - row * 96;
        float v = xT[row * 97 + col];
        xT[row * 97 + col] = (v - mA[row]) * iA[row] * g[col] + bt[col];
    }
    __syncthreads();
    int tc = threadIdx.x & 15, tr = threadIdx.x >> 4;
    float acc[4][6] = {};
    for (int k = 0; k < 96; ++k) {
        float xv[4], wv[6];
#pragma unroll
        for (int i = 0; i < 4; ++i) xv[i] = xT[(4 * tr + i) * 97 + k];
#pragma unroll
        for (int j = 0; j < 6; ++j) wv[j] = wT[(tc + 16 * j) * 100 + k];
#pragma unroll
        for (int i = 0; i < 4; ++i)
#pragma unroll
            for (int j = 0; j < 6; ++j) acc[i][j] = fmaf(xv[i], wv[j], acc[i][j]);
    }
    int pos = pos0 + 4 * tr;
    if (c0 < DINC) {
#pragma unroll
        for (int j = 0; j < 6; ++j) {
            int col = c0 + tc + 16 * j;
            float4 v = make_float4(acc[0][j], acc[1][j], acc[2][j], acc[3][j]);
            *(float4*)&xcr[((size_t)b * DINC + col) * LL + pos] = v;
        }
    } else {
#pragma unroll
        for (int i = 0; i < 4; ++i)
#pragma unroll
            for (int j = 0; j < 6; ++j) {
                int zc = c0 - DINC + tc + 16 * j;
                zs[(size_t)(row0 + 4 * tr + i) * DINC + zc] = siluf(acc[i][j]);
            }
    }
}

// ---------- 2. depthwise 3x3 conv + silu -> xconv ----------
__global__ __launch_bounds__(448) void dwconv_k(const float* __restrict__ xcr,
                                                const float* __restrict__ cw,
                                                const float* __restrict__ cb,
                                                float* __restrict__ xconv) {
    __shared__ float P[56 * 57];
    int bd = blockIdx.x;
    int d = bd % DINC;
    size_t base = (size_t)bd * LL;
    for (int t = threadIdx.x; t < LL; t += 448)
        P[(t / 56) * 57 + (t % 56)] = xcr[base + t];
    float wk[9];
#pragma unroll
    for (int q = 0; q < 9; ++q) wk[q] = cw[d * 9 + q];
    float bias = cb[d];
    __syncthreads();
    for (int t = threadIdx.x; t < LL; t += 448) {
        int h = t / 56, w = t % 56;
        float acc = bias;
#pragma unroll
        for (int ky = 0; ky < 3; ++ky) {
            int y = h + ky - 1;
            if ((unsigned)y >= 56u) continue;
#pragma unroll
            for (int kx = 0; kx < 3; ++kx) {
                int xq = w + kx - 1;
                if ((unsigned)xq >= 56u) continue;
                acc = fmaf(wk[ky * 3 + kx], P[y * 57 + xq], acc);
            }
        }
        xconv[base + t] = siluf(acc);
    }
}

// ---------- 3. x_proj GEMM, band = direction. grid (196,4) x 256. M=32,N=38 ----------
__global__ __launch_bounds__(256) void gemmx_k(const float* __restrict__ xconv,
                                               const float* __restrict__ xpw,
                                               float* __restrict__ dts,
                                               float* __restrict__ bcB,
                                               float* __restrict__ bcC,
                                               float* __restrict__ xscanT) {
    __shared__ float xT[32 * 49];
    __shared__ float wT[38 * 52];
    int row0 = blockIdx.x * 32;
    int b = row0 / LL, pos0 = row0 % LL;
    int by = blockIdx.y;               // direction k
    int m = threadIdx.x & 31, cg = threadIdx.x >> 5;
    float acc[5] = {};
    for (int kc = 0; kc < 4; ++kc) {
        if (kc) __syncthreads();
        for (int f = threadIdx.x; f < 48 * 8; f += 256) {
            int dd = f >> 3, po = (f & 7) * 4;
            float4 v = *(const float4*)&xconv[((size_t)b * DINC + kc * 48 + dd) * LL + pos0 + po];
            xT[(po + 0) * 49 + dd] = v.x; xT[(po + 1) * 49 + dd] = v.y;
            xT[(po + 2) * 49 + dd] = v.z; xT[(po + 3) * 49 + dd] = v.w;
        }
        for (int f = threadIdx.x; f < 38 * 12; f += 256) {
            int r = f / 12, kq = (f % 12) * 4;
            *(float4*)&wT[r * 52 + kq] =
                *(const float4*)&xpw[(size_t)(by * 38 + r) * DINC + kc * 48 + kq];
        }
        __syncthreads();
#pragma unroll 4
        for (int k = 0; k < 48; ++k) {
            float xv = xT[m * 49 + k];
#pragma unroll
            for (int j = 0; j < 5; ++j) {
                int idx = cg + 8 * j;
                float wv = (idx < 38) ? wT[idx * 52 + k] : 0.f;
                acc[j] = fmaf(xv, wv, acc[j]);
            }
        }
        if (by == 0) {
            // emit 2 xscan_T slices for this 48-d band (xT holds [pos][d])
            for (int f = threadIdx.x; f < 32 * 48; f += 256) {
                int i = f / 48, dd = f - 48 * (f / 48);
                float v = xT[i * 49 + dd];
                int pos = pos0 + i;
                int hh = pos / 56, w = pos - 56 * hh;
                int lt = w * 56 + hh;
                size_t bb = (size_t)b * 2;
                int col = kc * 48 + dd;
                xscanT[(bb * LL + pos) * DINC + col] = v;
                xscanT[((bb + 1) * LL + lt) * DINC + col] = v;
            }
        }
    }
    {
        int pos = pos0 + m;
        int h = pos / 56, w = pos - 56 * h;
        int lt = w * 56 + h;
        int l = (by == 0) ? pos : (by == 1) ? lt : (by == 2) ? (LL - 1 - pos) : (LL - 1 - lt);
        size_t rb = (size_t)(b * KDIR + by) * LL + l;
#pragma unroll
        for (int j = 0; j < 5; ++j) {
            int idx = cg + 8 * j;
            if (idx >= 38) continue;
            float v = acc[j];
            if (idx < DTRC)    dts[rb * DTRC + idx] = v;
            else if (idx < 22) bcB[rb * NSTC + (idx - 6)] = v;
            else               bcC[rb * NSTC + (idx - 22)] = v;
        }
    }
}

// ---------- 4a. pass1: d-per-thread local scan. grid 8*3*98 = 2352 x 64 ----------
__global__ __launch_bounds__(64) void pass1_k(const float* __restrict__ dts,
                                              const float* __restrict__ bcB,
                                              const float* __restrict__ bcC,
                                              const float* __restrict__ alog,
                                              const float* __restrict__ dtw,
                                              const float* __restrict__ dtb,
                                              const float* __restrict__ xscanT,
                                              float* __restrict__ hendT,
                                              float* __restrict__ sumdT,
                                              float* __restrict__ ysT,
                                              float* __restrict__ cumdT) {
    __shared__ float sdt[LC * 7];
    __shared__ float sB[LC * 16];
    __shared__ float sC[LC * 16];
    int blk = blockIdx.x;
    int c = blk % NCH;
    int dtile = (blk / NCH) % 3;
    int bk = blk / (NCH * 3);
    int k = bk & 3, b = bk >> 2;
    int l0 = c * LC;
    int t = threadIdx.x;
    int d = dtile * 64 + t;
    const float* dsrc = dts + ((size_t)bk * LL + l0) * DTRC;
    for (int f = t; f < LC * DTRC; f += 64) sdt[(f / DTRC) * 7 + (f % DTRC)] = dsrc[f];
    const float* bB = bcB + ((size_t)bk * LL + l0) * NSTC;
    const float* bC = bcC + ((size_t)bk * LL + l0) * NSTC;
    for (int f = t; f < LC * NSTC; f += 64) { sB[f] = bB[f]; sC[f] = bC[f]; }
    float wr[DTRC];
    {
        const float* wp = dtw + ((size_t)k * DINC + d) * DTRC;
#pragma unroll
        for (int r = 0; r < DTRC; ++r) wr[r] = wp[r];
    }
    float bias = dtb[k * DINC + d];
    float An2[NSTC];
    {
        const float* ap = alog + ((size_t)(k * DINC + d)) * NSTC;
#pragma unroll
        for (int n = 0; n < NSTC; ++n) An2[n] = -__expf(ap[n]) * LOG2E;
    }
    __syncthreads();
    float h[NSTC];
#pragma unroll
    for (int n = 0; n < NSTC; ++n) h[n] = 0.f;
    float cum = 0.f;
    bool rev = (k >= 2);
    const float* xbase = xscanT + ((size_t)(b * 2 + (k & 1)) * LL) * DINC + d;
    int xi0 = rev ? (LL - 1 - l0) : l0;
    float* yrow = ysT + ((size_t)bk * LL + l0) * DINC + d;
    float* crow = cumdT + ((size_t)bk * LL + l0) * DINC + d;
#pragma unroll 8
    for (int s = 0; s < LC; ++s) {
        float acc = bias;
#pragma unroll
        for (int r = 0; r < DTRC; ++r) acc = fmaf(wr[r], sdt[s * 7 + r], acc);
        float dv = softplusf(acc);
        float xv = xbase[(size_t)(rev ? (xi0 - s) : (xi0 + s)) * DINC];
        cum += dv;
        float dx = dv * xv;
        const float4* B4 = (const float4*)&sB[s * 16];
        const float4* C4 = (const float4*)&sC[s * 16];
        float y = 0.f;
#pragma unroll
        for (int nq = 0; nq < 4; ++nq) {
            float4 Bv = B4[nq], Cv = C4[nq];
            float e0 = fexp2(An2[nq * 4 + 0] * dv);
            h[nq * 4 + 0] = fmaf(e0, h[nq * 4 + 0], dx * Bv.x);
            y = fmaf(h[nq * 4 + 0], Cv.x, y);
            float e1 = fexp2(An2[nq * 4 + 1] * dv);
            h[nq * 4 + 1] = fmaf(e1, h[nq * 4 + 1], dx * Bv.y);
            y = fmaf(h[nq * 4 + 1], Cv.y, y);
            float e2 = fexp2(An2[nq * 4 + 2] * dv);
            h[nq * 4 + 2] = fmaf(e2, h[nq * 4 + 2], dx * Bv.z);
            y = fmaf(h[nq * 4 + 2], Cv.z, y);
            float e3 = fexp2(An2[nq * 4 + 3] * dv);
            h[nq * 4 + 3] = fmaf(e3, h[nq * 4 + 3], dx * Bv.w);
            y = fmaf(h[nq * 4 + 3], Cv.w, y);
        }
        yrow[(size_t)s * DINC] = y;
        crow[(size_t)s * DINC] = cum;
    }
#pragma unroll
    for (int n = 0; n < NSTC; ++n)
        hendT[((size_t)(bk * NCH + c) * NSTC + n) * DINC + d] = h[n];
    sumdT[(size_t)(bk * NCH + c) * DINC + d] = cum;
}

// ---------- 4b. scan2: thread=(d,n), serial over chunks. grid 96 x 256 ----------
__global__ __launch_bounds__(256) void scan2_k(float* __restrict__ hendT,
                                               const float* __restrict__ sumdT,
                                               const float* __restrict__ alog) {
    int gid = blockIdx.x * 256 + threadIdx.x;
    int d = gid % DINC;
    int n = (gid / DINC) % NSTC;
    int bk = gid / (DINC * NSTC);
    int k = bk & 3;
    float An2 = -__expf(alog[((size_t)(k * DINC + d)) * NSTC + n]) * LOG2E;
    float h = 0.f;
#pragma unroll 4
    for (int c = 0; c < NCH; ++c) {
        size_t idx = ((size_t)(bk * NCH + c) * NSTC + n) * DINC + d;
        float he = hendT[idx];
        float sd = sumdT[(size_t)(bk * NCH + c) * DINC + d];
        hendT[idx] = h;
        h = fmaf(fexp2(An2 * sd), h, he);
    }
}

// ---------- 4c. pass2: y += sum_n C*exp2(A2*cumd)*hpre. grid 784 x 256 ----------
__global__ __launch_bounds__(256) void pass2_k(const float* __restrict__ bcC,
                                               const float* __restrict__ alog,
                                               const float* __restrict__ hpreT,
                                               const float* __restrict__ cumdT,
                                               float* __restrict__ ysT) {
    __shared__ float sA2[DINC * 17];
    __shared__ float sH[DINC * 17];
    __shared__ float sC[LC * NSTC];
    int blk = blockIdx.x;
    int c = blk % NCH;
    int bk = blk / NCH;
    int k = bk & 3;
    int l0 = c * LC;
    int tid = threadIdx.x;
    const float* ap = alog + (size_t)k * DINC * NSTC;
    for (int f = tid; f < DINC * NSTC; f += 256) {
        int dq = f / NSTC, n = f % NSTC;
        sA2[dq * 17 + n] = -__expf(ap[f]) * LOG2E;
    }
    for (int f = tid; f < DINC * NSTC; f += 256) {
        int n = f / DINC, dq = f % DINC;
        sH[dq * 17 + n] = hpreT[((size_t)(bk * NCH + c) * NSTC + n) * DINC + dq];
    }
    const float* bC = bcC + ((size_t)bk * LL + l0) * NSTC;
    for (int f = tid; f < LC * NSTC; f += 256) sC[f] = bC[f];
    __syncthreads();
    for (int e = tid; e < LC * DINC; e += 256) {
        int li = e / DINC, d = e - DINC * (e / DINC);
        size_t gq = ((size_t)bk * LL + l0 + li) * DINC + d;
        float cd = cumdT[gq];
        float y = ysT[gq];
        const float* A = &sA2[d * 17];
        const float* Hp = &sH[d * 17];
        const float* Cp = &sC[li * NSTC];
#pragma unroll
        for (int n = 0; n < NSTC; ++n)
            y = fmaf(Hp[n] * fexp2(A[n] * cd), Cp[n], y);
        ysT[gq] = y;
    }
}

// ---------- 5. fused combine + out_norm*silu(z) + out_proj + residual. M=16, grid 392 ----------
__global__ __launch_bounds__(256) void gemm2_k(const float* __restrict__ ysT,
                                               const float* __restrict__ xscanT,
                                               const float* __restrict__ dsv,
                                               const float* __restrict__ g,
                                               const float* __restrict__ bt,
                                               const float* __restrict__ zs,
                                               const float* __restrict__ opw,
                                               const float* __restrict__ x,
                                               const float* __restrict__ sc1,
                                               float* __restrict__ vl) {
    __shared__ float xT[16 * 193];
    __shared__ float wT[96 * 52];
    __shared__ float mA[16], iA[16];
    __shared__ float sD[DINC];
    int row0 = blockIdx.x * 16;
    int b = row0 / LL, pos0 = row0 % LL;
    if (threadIdx.x < DINC)
        sD[threadIdx.x] = dsv[threadIdx.x] + dsv[DINC + threadIdx.x] +
                          dsv[2 * DINC + threadIdx.x] + dsv[3 * DINC + threadIdx.x];
    __syncthreads();
    size_t base = (size_t)b * KDIR * LL;
    size_t xbase = (size_t)b * 2 * LL;
    for (int f = threadIdx.x; f < 16 * DINC; f += 256) {
        int r = f / DINC, d = f - DINC * (f / DINC);
        int pos = pos0 + r;
        int hh = pos / 56, w = pos - 56 * hh;
        int lt = w * 56 + hh;
        float y = ysT[(base + pos) * DINC + d]
                + ysT[(base + LL + lt) * DINC + d]
                + ysT[(base + 2 * LL + (LL - 1 - pos)) * DINC + d]
                + ysT[(base + 3 * LL + (LL - 1 - lt)) * DINC + d];
        float xv = xscanT[(xbase + pos) * DINC + d];  // slice 0 = xconv at [pos][d]
        xT[r * 193 + d] = fmaf(xv, sD[d], y);
    }
    __syncthreads();
    // wave-parallel LN stats: 16 rows x 16 lanes
    {
        int r = threadIdx.x >> 4, sc = threadIdx.x & 15;
        float s = 0.f, q = 0.f;
#pragma unroll
        for (int j = 0; j < 12; ++j) {
            float v = xT[r * 193 + sc + 16 * j];
            s += v; q = fmaf(v, v, q);
        }
        s += __shfl_xor(s, 1, 16); q += __shfl_xor(q, 1, 16);
        s += __shfl_xor(s, 2, 16); q += __shfl_xor(q, 2, 16);
        s += __shfl_xor(s, 4, 16); q += __shfl_xor(q, 4, 16);
        s += __shfl_xor(s, 8, 16); q += __shfl_xor(q, 8, 16);
        if (sc == 0) {
            float m = s * (1.f / 192.f);
            mA[r] = m;
            iA[r] = rsqrtf(q * (1.f / 192.f) - m * m + EPSF);
        }
    }
    __syncthreads();
    for (int e = threadIdx.x; e < 16 * 192; e += 256) {
        int row = e / 192, col = e - row * 192;
        float v = xT[row * 193 + col];
        float z = zs[(size_t)row0 * DINC + e];
        xT[row * 193 + col] = ((v - mA[row]) * iA[row] * g[col] + bt[col]) * z;
    }
    int tc = threadIdx.x & 15, tr = threadIdx.x >> 4;
    float acc[6] = {};
    for (int kc = 0; kc < 4; ++kc) {
        __syncthreads();
        for (int f = threadIdx.x; f < 96 * 12; f += 256) {
            int r = f / 12, kq = (f % 12) * 4;
            *(float4*)&wT[r * 52 + kq] = *(const float4*)&opw[(size_t)r * DINC + kc * 48 + kq];
        }
        __syncthreads();
#pragma unroll 4
        for (int k = 0; k < 48; ++k) {
            float xv = xT[tr * 193 + kc * 48 + k];
#pragma unroll
            for (int j = 0; j < 6; ++j) acc[j] = fmaf(xv, wT[(tc + 16 * j) * 52 + k], acc[j]);
        }
    }
    {
        int pos = pos0 + tr;
#pragma unroll
        for (int j = 0; j < 6; ++j) {
            int col = tc + 16 * j;
            float v = fmaf(sc1[col], x[((size_t)b * DIMC + col) * LL + pos], acc[j]);
            vl[(size_t)(row0 + tr) * DIMC + col] = v;
        }
    }
}

// ---------- 6. LN2 + conv1x1(96->24) + BN + ReLU ----------
__global__ __launch_bounds__(256) void ln2conv1_k(const float* __restrict__ vl,
                                                  const float* __restrict__ g,
                                                  const float* __restrict__ bt,
                                                  const float* __restrict__ w1,
                                                  const float* __restrict__ g1,
                                                  const float* __restrict__ b1,
                                                  const float* __restrict__ m1,
                                                  const float* __restrict__ v1,
                                                  float* __restrict__ h1) {
    __shared__ float row[4][96];
    int wv = threadIdx.x >> 6, lane = threadIdx.x & 63;
    int pix = blockIdx.x * 4 + wv;
    const float* vr = vl + (size_t)pix * DIMC;
    float a0 = vr[lane];
    float a1 = (lane < 32) ? vr[64 + lane] : 0.f;
    float s = a0 + a1, q = a0 * a0 + a1 * a1;
    for (int o = 32; o; o >>= 1) { s += __shfl_xor(s, o, 64); q += __shfl_xor(q, o, 64); }
    float m = s * (1.f / 96.f);
    float inv = rsqrtf(q * (1.f / 96.f) - m * m + EPSF);
    row[wv][lane] = (a0 - m) * inv * g[lane] + bt[lane];
    if (lane < 32) row[wv][64 + lane] = (a1 - m) * inv * g[64 + lane] + bt[64 + lane];
    __syncthreads();
    if (lane < 24) {
        const float* wr = w1 + lane * 96;
        float acc = 0.f;
#pragma unroll 8
        for (int c = 0; c < 96; ++c) acc = fmaf(row[wv][c], wr[c], acc);
        float bn = (acc - m1[lane]) * rsqrtf(v1[lane] + EPSF) * g1[lane] + b1[lane];
        int b = pix / LL, pos = pix % LL;
        h1[((size_t)b * 24 + lane) * LL + pos] = fmaxf(bn, 0.f);
    }
}

// ---------- 7. conv3x3 (24->24) + BN + ReLU ----------
__global__ __launch_bounds__(256) void conv2_k(const float* __restrict__ h1,
                                               const float* __restrict__ w2,
                                               const float* __restrict__ g2,
                                               const float* __restrict__ b2,
                                               const float* __restrict__ m2,
                                               const float* __restrict__ v2,
                                               float* __restrict__ h2) {
    int i = blockIdx.x * 256 + threadIdx.x;
    int pos = i % LL, mo = (i / LL) % 24, b = i / (LL * 24);
    int hh = pos / WWD, ww = pos % WWD;
    float acc = 0.f;
    for (int c = 0; c < 24; ++c) {
        const float* src = h1 + ((size_t)b * 24 + c) * LL;
        const float* wk = w2 + ((size_t)(mo * 24 + c)) * 9;
#pragma unroll
        for (int ky = 0; ky < 3; ++ky) {
            int y = hh + ky - 1;
            if ((unsigned)y >= HH) continue;
#pragma unroll
            for (int kx = 0; kx < 3; ++kx) {
                int xq = ww + kx - 1;
                if ((unsigned)xq >= WWD) continue;
                acc = fmaf(wk[ky * 3 + kx], src[y * WWD + xq], acc);
            }
        }
    }
    float bn = (acc - m2[mo]) * rsqrtf(v2[mo] + EPSF) * g2[mo] + b2[mo];
    h2[i] = fmaxf(bn, 0.f);
}

// ---------- 8. conv1x1 (24->96) + BN ----------
__global__ __launch_bounds__(256) void conv3_k(const float* __restrict__ h2,
                                               const float* __restrict__ w3,
                                               const float* __restrict__ g3,
                                               const float* __restrict__ b3,
                                               const float* __restrict__ m3,
                                               const float* __restrict__ v3,
                                               float* __restrict__ h3) {
    int i = blockIdx.x * 256 + threadIdx.x;
    int pos = i % LL, c = (i / LL) % DIMC, b = i / (LL * DIMC);
    const float* wr = w3 + c * 24;
    float acc = 0.f;
#pragma unroll
    for (int mo = 0; mo < 24; ++mo)
        acc = fmaf(wr[mo], h2[((size_t)b * 24 + mo) * LL + pos], acc);
    h3[i] = (acc - m3[c]) * rsqrtf(v3[c] + EPSF) * g3[c] + b3[c];
}

// ---------- 9. SE pool ----------
__global__ __launch_bounds__(256) void pool_k(const float* __restrict__ h3,
                                              float* __restrict__ pooled) {
    int bc = blockIdx.x;
    const float* p = h3 + (size_t)bc * LL;
    float s = 0.f;
    for (int i = threadIdx.x; i < LL; i += 256) s += p[i];
    for (int o = 32; o; o >>= 1) s += __shfl_xor(s, o, 64);
    __shared__ float wsum[4];
    if ((threadIdx.x & 63) == 0) wsum[threadIdx.x >> 6] = s;
    __syncthreads();
    if (threadIdx.x == 0) pooled[bc] = (wsum[0] + wsum[1] + wsum[2] + wsum[3]) * (1.f / 3136.f);
}

// ---------- 10. SE MLP ----------
__global__ __launch_bounds__(128) void semlp_k(const float* __restrict__ pooled,
                                               const float* __restrict__ sw1,
                                               const float* __restrict__ sw2,
                                               float* __restrict__ sew) {
    __shared__ float pl[2][96];
    __shared__ float hid[2][24];
    for (int i = threadIdx.x; i < 192; i += 128) pl[i / 96][i % 96] = pooled[i];
    __syncthreads();
    if (threadIdx.x < 48) {
        int b = threadIdx.x / 24, mo = threadIdx.x % 24;
        float acc = 0.f;
        for (int c = 0; c < 96; ++c) acc = fmaf(pl[b][c], sw1[mo * 96 + c], acc);
        hid[b][mo] = fmaxf(acc, 0.f);
    }
    __syncthreads();
    for (int i = threadIdx.x; i < 192; i += 128) {
        int b = i / 96, c = i % 96;
        float acc = 0.f;
        for (int mo = 0; mo < 24; ++mo) acc = fmaf(hid[b][mo], sw2[c * 24 + mo], acc);
        sew[i] = 1.f / (1.f + __expf(-acc));
    }
}

// ---------- 11. final ----------
__global__ __launch_bounds__(256) void final_k(const float* __restrict__ h3,
                                               const float* __restrict__ sew,
                                               const float* __restrict__ vl,
                                               const float* __restrict__ sc2,
                                               float* __restrict__ out) {
    int i = blockIdx.x * 256 + threadIdx.x;
    int pos = i % LL, c = (i / LL) % DIMC, b = i / (LL * DIMC);
    out[i] = fmaf(h3[i], sew[b * DIMC + c],
                  sc2[c] * vl[((size_t)b * LL + pos) * DIMC + c]);
}

extern "C" void kernel_launch(void* const* d_in, const int* in_sizes, int n_in,
                              void* d_out, int out_size, void* d_ws, size_t ws_size,
                              hipStream_t stream) {
    const float* x    = (const float*)d_in[0];
    const float* n1g  = (const float*)d_in[1];
    const float* n1b  = (const float*)d_in[2];
    const float* ipw  = (const float*)d_in[3];
    const float* cw   = (const float*)d_in[4];
    const float* cb   = (const float*)d_in[5];
    const float* xpw  = (const float*)d_in[6];
    const float* dtw  = (const float*)d_in[7];
    const float* dtb  = (const float*)d_in[8];
    const float* alog = (const float*)d_in[9];
    const float* dsv  = (const float*)d_in[10];
    const float* ong  = (const float*)d_in[11];
    const float* onb  = (const float*)d_in[12];
    const float* opw  = (const float*)d_in[13];
    const float* sc1  = (const float*)d_in[14];
    const float* n2g  = (const float*)d_in[15];
    const float* n2b  = (const float*)d_in[16];
    const float* w1   = (const float*)d_in[17];
    const float* g1   = (const float*)d_in[18];
    const float* b1   = (const float*)d_in[19];
    const float* m1   = (const float*)d_in[20];
    const float* v1   = (const float*)d_in[21];
    const float* w2   = (const float*)d_in[22];
    const float* g2   = (const float*)d_in[23];
    const float* b2   = (const float*)d_in[24];
    const float* m2   = (const float*)d_in[25];
    const float* v2   = (const float*)d_in[26];
    const float* w3   = (const float*)d_in[27];
    const float* g3   = (const float*)d_in[28];
    const float* b3   = (const float*)d_in[29];
    const float* m3   = (const float*)d_in[30];
    const float* v3   = (const float*)d_in[31];
    const float* sw1  = (const float*)d_in[32];
    const float* sw2  = (const float*)d_in[33];
    const float* sc2  = (const float*)d_in[34];
    float* ws = (float*)d_ws;
    float* out = (float*)d_out;

    gemm1_k<<<dim3(NPIX / 64, 4), 256, 0, stream>>>(x, n1g, n1b, ipw,
                                                    ws + OFF_XCRAW, ws + OFF_ZS);
    dwconv_k<<<BB * DINC, 448, 0, stream>>>(ws + OFF_XCRAW, cw, cb, ws + OFF_XCONV);
    gemmx_k<<<dim3(NPIX / 32, 4), 256, 0, stream>>>(ws + OFF_XCONV, xpw, ws + OFF_DTS,
                                                    ws + OFF_BCB, ws + OFF_BCC, ws + OFF_XSCANT);

    pass1_k<<<BB * KDIR * 3 * NCH, 64, 0, stream>>>(
        ws + OFF_DTS, ws + OFF_BCB, ws + OFF_BCC, alog, dtw, dtb,
        ws + OFF_XSCANT, ws + OFF_HENDT, ws + OFF_SUMDT, ws + OFF_YS, ws + OFF_CUMD);
    scan2_k<<<(NCHAIN * NSTC) / 256, 256, 0, stream>>>(ws + OFF_HENDT, ws + OFF_SUMDT, alog);
    pass2_k<<<BB * KDIR * NCH, 256, 0, stream>>>(
        ws + OFF_BCC, alog, ws + OFF_HENDT, ws + OFF_CUMD, ws + OFF_YS);

    gemm2_k<<<NPIX / 16, 256, 0, stream>>>(ws + OFF_YS, ws + OFF_XSCANT, dsv,
                                           ong, onb, ws + OFF_ZS, opw, x, sc1, ws + OFF_VL);
    ln2conv1_k<<<NPIX / 4, 256, 0, stream>>>(ws + OFF_VL, n2g, n2b, w1, g1, b1, m1, v1,
                                             ws + OFF_H1);
    conv2_k<<<(BB * 24 * LL) / 256, 256, 0, stream>>>(ws + OFF_H1, w2, g2, b2, m2, v2,
                                                      ws + OFF_H2);
    conv3_k<<<(BB * DIMC * LL) / 256, 256, 0, stream>>>(ws + OFF_H2, w3, g3, b3, m3, v3,
                                                        ws + OFF_H3);
    pool_k<<<BB * DIMC, 256, 0, stream>>>(ws + OFF_H3, ws + OFF_POOL);
    semlp_k<<<1, 128, 0, stream>>>(ws + OFF_POOL, sw1, sw2, ws + OFF_SEW);
    final_k<<<(BB * DIMC * LL) / 256, 256, 0, stream>>>(ws + OFF_H3, ws + OFF_SEW, ws + OFF_VL,
                                                        sc2, out);
    (void)in_sizes; (void)n_in; (void)out_size; (void)ws_size;
}